// Round 6
// baseline (478.560 us; speedup 1.0000x reference)
//
#include <hip/hip_runtime.h>
#include <cmath>

typedef _Float16 half8 __attribute__((ext_vector_type(8)));
typedef _Float16 half4v __attribute__((ext_vector_type(4)));
typedef __attribute__((ext_vector_type(4))) float floatx4;

#define GLOAD_LDS16(gp, lp)                                            \
  __builtin_amdgcn_global_load_lds(                                    \
      (const __attribute__((address_space(1))) void*)(gp),             \
      (__attribute__((address_space(3))) void*)(lp), 16, 0, 0)

static inline int cdiv(int a, int b) { return (a + b - 1) / b; }

// SESSION NOTES (do not repeat failed experiments):
//  r1/r2: 256x256 8-phase 1-block/CU gemm8 (T3+T4+T5) regressed (MfmaUtil 33->24%).
//         At K=1024 / 512-block shapes the deep pipeline never fills and 1-block/CU
//         has no TLP cover; gemm_nt's 4-block/CU TLP wins.
//  r3: XCD-chunked block swizzle (T1): FETCH 136->52 MB as predicted but dur 92->107us.
//      Inputs are L3-fit (36 MB); swizzle trades L3-shared hits for per-XCD L2 thrash.
//  r4: stream-K fixup (threadfence+atomic counter) in split-K: L1-PART 90->310us,
//      FETCH +65MB. Device-scope fences invalidate L2 for co-resident blocks. NEVER
//      put device-scope fences in a cache-hot kernel's epilogue.
//  r5: lvl2/lvl3 launch merges of independent kernels: 483->454us. Launch-gap
//      reduction is the live lever; GEMMs are at the structure floor (744 TF).
//  gemm_nt 128x128 @ 4 blocks/CU = 744 TF here (~82% of the structure's 912 TF
//  ceiling; rest is K=1024 short-loop overhead). Treat as GEMM floor.

// ------- merged prep: cast h0/W1/W2/W3 fp32->fp16, then centers cast + norms -------
__global__ void prep(const float* __restrict__ h0, const float* __restrict__ W1,
                     const float* __restrict__ W2, const float* __restrict__ W3,
                     const float* __restrict__ c1, const float* __restrict__ c2,
                     const float* __restrict__ c3,
                     _Float16* __restrict__ hh, _Float16* __restrict__ Wh1,
                     _Float16* __restrict__ Wh2, _Float16* __restrict__ Wh3,
                     _Float16* __restrict__ cb1, _Float16* __restrict__ cb2,
                     _Float16* __restrict__ cb3,
                     float* __restrict__ cn1, float* __restrict__ cn2,
                     float* __restrict__ cn3,
                     int nh, int nw, int castBlocks, int n1, int n2) {
  int t = threadIdx.x;
  if ((int)blockIdx.x < castBlocks) {
    int gi = (blockIdx.x * 256 + t) * 4;
    const float* src; _Float16* dst; int off;
    if (gi < nh)                { src = h0; dst = hh;  off = gi; }
    else if (gi < nh + nw)      { src = W1; dst = Wh1; off = gi - nh; }
    else if (gi < nh + 2 * nw)  { src = W2; dst = Wh2; off = gi - nh - nw; }
    else if (gi < nh + 3 * nw)  { src = W3; dst = Wh3; off = gi - nh - 2 * nw; }
    else return;
    float4 v = *(const float4*)(src + off);
    half4v o = {(_Float16)v.x, (_Float16)v.y, (_Float16)v.z, (_Float16)v.w};
    *(half4v*)(dst + off) = o;
    return;
  }
  int row = blockIdx.x - castBlocks;
  const float* c; _Float16* cb; float* cn;
  if (row < n1)            { c = c1; cb = cb1; cn = cn1; }
  else if (row < n1 + n2)  { row -= n1; c = c2; cb = cb2; cn = cn2; }
  else                     { row -= n1 + n2; c = c3; cb = cb3; cn = cn3; }
  float4 v = *(const float4*)(c + (size_t)row * 1024 + t * 4);
  half4v o = {(_Float16)v.x, (_Float16)v.y, (_Float16)v.z, (_Float16)v.w};
  *(half4v*)(cb + (size_t)row * 1024 + t * 4) = o;
  float s = v.x * v.x + v.y * v.y + v.z * v.z + v.w * v.w;
  #pragma unroll
  for (int off = 32; off > 0; off >>= 1) s += __shfl_down(s, off, 64);
  __shared__ float ws[4];
  if ((t & 63) == 0) ws[t >> 6] = s;
  __syncthreads();
  if (t == 0) cn[row] = ws[0] + ws[1] + ws[2] + ws[3];
}

// ------------- L1 softmax pass: finalize max from per-block pmax, exp in place, partial sums -------------
#define SM_CHUNK 64
__global__ void colexp_partial(_Float16* __restrict__ ST, const float* __restrict__ pmax,
                               float* __restrict__ psum, int mchunks, int ncur, int nprev) {
  int col = (blockIdx.x * 256 + threadIdx.x) * 4;
  if (col >= nprev) return;
  float m0 = -1e30f, m1 = -1e30f, m2 = -1e30f, m3 = -1e30f;
  for (int k = 0; k < mchunks; ++k) {
    float4 v = *(const float4*)(pmax + (size_t)k * nprev + col);
    m0 = fmaxf(m0, v.x); m1 = fmaxf(m1, v.y); m2 = fmaxf(m2, v.z); m3 = fmaxf(m3, v.w);
  }
  int j0 = blockIdx.y * SM_CHUNK;
  int j1 = min(j0 + SM_CHUNK, ncur);
  float s0 = 0.f, s1 = 0.f, s2 = 0.f, s3 = 0.f;
  for (int j = j0; j < j1; ++j) {
    size_t o = (size_t)j * nprev + col;
    half4v x = *(const half4v*)(ST + o);
    float e0 = __expf((float)x[0] - m0), e1 = __expf((float)x[1] - m1);
    float e2 = __expf((float)x[2] - m2), e3 = __expf((float)x[3] - m3);
    half4v e = {(_Float16)e0, (_Float16)e1, (_Float16)e2, (_Float16)e3};
    *(half4v*)(ST + o) = e;   // in place: same thread reads then writes same elem
    s0 += e0; s1 += e1; s2 += e2; s3 += e3;
  }
  float4 sv = {s0, s1, s2, s3};
  *(float4*)(psum + (size_t)blockIdx.y * nprev + col) = sv;
}

// ---------------- split-K reduce: out_fp16[i] = sum_s part[s][i] (fp16 partials) ----------------
__global__ void reduce_parts(const _Float16* __restrict__ part, _Float16* __restrict__ out,
                             int mn, int S) {
  int i = (blockIdx.x * 256 + threadIdx.x) * 4;
  if (i >= mn) return;
  float a0 = 0.f, a1 = 0.f, a2 = 0.f, a3 = 0.f;
  for (int s = 0; s < S; ++s) {
    half4v v = *(const half4v*)(part + (size_t)s * mn + i);
    a0 += (float)v[0]; a1 += (float)v[1]; a2 += (float)v[2]; a3 += (float)v[3];
  }
  half4v o = {(_Float16)a0, (_Float16)a1, (_Float16)a2, (_Float16)a3};
  *(half4v*)(out + i) = o;
}

enum { EP_LOGIT = 0, EP_TANH = 1, EP_TANHP = 2, EP_F16 = 3, EP_F32 = 4, EP_PART = 5 };

// ---------------- NT fp16 MFMA GEMM body: C[M][N] = A[M][K] * B[N][K]^T ----------------
// global_load_lds (16B) staging, XOR-swizzled LDS (0 bank conflicts). Pristine
// epilogue — no fences, no atomics (see r4 note above).
template<int BM, int BN, int EPI>
__device__ __forceinline__ void gemm_body(
    const _Float16* __restrict__ A, const _Float16* __restrict__ B,
    void* __restrict__ Cout,
    const float* __restrict__ aux1,   // cn[M] or bias[M]
    const float* __restrict__ aux2,   // psum (EP_TANH)
    float* __restrict__ pmax,         // EP_LOGIT out
    int pnchunks,                     // EP_TANH psum chunk count
    int M, int N, int K, int kLen,
    int bx, int by, int bz,
    _Float16* As, _Float16* Bs) {
  constexpr int BK = 64;                 // 128 B/row, unpadded (global_load_lds needs it)
  constexpr int WTM = BM / 2, WTN = BN / 2;
  constexpr int FM = WTM / 16, FN = WTN / 16;
  float* smf = (float*)As;               // aliased: used only after the K-loop
  const int tid  = threadIdx.x;
  const int lane = tid & 63;
  const int wave = tid >> 6;             // 256 threads = 4 waves
  const int wm = wave >> 1, wn = wave & 1;
  const int mBase = bx * BM, nBase = by * BN;
  const int kBase = bz * kLen;
  const int lr    = lane & 15;           // fragment row (A: m, B: n)
  const int kHalf = (lane >> 4) << 3;    // fragment k offset: 0,8,16,24

  const int srOff  = lane >> 3;                        // row within 8-row staging group
  const int schunk = (lane & 7) ^ srOff;               // swizzled global K-chunk
  floatx4 acc[FM][FN] = {};
  constexpr int AV = BM * BK / (256 * 8);
  constexpr int BV = BN * BK / (256 * 8);

  for (int k0 = kBase; k0 < kBase + kLen; k0 += BK) {  // kLen % 64 == 0 everywhere
    #pragma unroll
    for (int v = 0; v < AV; ++v) {
      int rowBase = v * 32 + wave * 8;
      int gm = mBase + rowBase + srOff;
      if (gm >= M) gm = M - 1;                         // clamp: feeds only discarded rows
      GLOAD_LDS16(A + (size_t)gm * K + k0 + schunk * 8, &As[rowBase * BK]);
    }
    #pragma unroll
    for (int v = 0; v < BV; ++v) {
      int rowBase = v * 32 + wave * 8;
      int gn = nBase + rowBase + srOff;
      if (gn >= N) gn = N - 1;
      GLOAD_LDS16(B + (size_t)gn * K + k0 + schunk * 8, &Bs[rowBase * BK]);
    }
    __syncthreads();
    #pragma unroll
    for (int kk = 0; kk < BK; kk += 32) {
      const int q = (kk + kHalf) >> 3;
      half8 af[FM], bfv[FN];
      #pragma unroll
      for (int i = 0; i < FM; ++i) {
        int r = wm * WTM + i * 16 + lr;
        af[i] = *(const half8*)(&As[r * BK + ((q ^ (r & 7)) << 3)]);
      }
      #pragma unroll
      for (int j = 0; j < FN; ++j) {
        int r = wn * WTN + j * 16 + lr;
        bfv[j] = *(const half8*)(&Bs[r * BK + ((q ^ (r & 7)) << 3)]);
      }
      #pragma unroll
      for (int i = 0; i < FM; ++i)
        #pragma unroll
        for (int j = 0; j < FN; ++j)
          acc[i][j] = __builtin_amdgcn_mfma_f32_16x16x32_f16(af[i], bfv[j], acc[i][j], 0, 0, 0);
    }
    __syncthreads();
  }
  // here: all waves past the final barrier; staging LDS is dead -> smf may alias it

  if (EPI == EP_TANH) {                  // linv[col] = 1 / sum_k psum[k][col]
    if (tid < BN) {
      int col = nBase + tid;
      float ssum = 0.f;
      if (col < N)
        for (int k = 0; k < pnchunks; ++k) ssum += aux2[(size_t)k * N + col];
      smf[tid] = 1.f / ssum;
    }
    __syncthreads();
  }

  // epilogue: D row=(lane>>4)*4+r, col=lane&15 (m89-verified mapping)
  const int rBase = (lane >> 4) << 2;
  float lmax[FN];
  #pragma unroll
  for (int j = 0; j < FN; ++j) lmax[j] = -1e30f;
  #pragma unroll
  for (int i = 0; i < FM; ++i) {
    #pragma unroll
    for (int j = 0; j < FN; ++j) {
      #pragma unroll
      for (int r = 0; r < 4; ++r) {
        int row = mBase + wm * WTM + i * 16 + rBase + r;
        int col = nBase + wn * WTN + j * 16 + lr;
        if (row < M && col < N) {
          float v = acc[i][j][r];
          size_t o = (size_t)row * N + col;
          if (EPI == EP_LOGIT) {
            v = 0.5f * v - 0.25f * aux1[row];
            ((_Float16*)Cout)[o] = (_Float16)v;
            lmax[j] = fmaxf(lmax[j], v);
          } else if (EPI == EP_TANH) {
            v = tanhf(v + aux1[row]) * smf[col - nBase];
            ((_Float16*)Cout)[o] = (_Float16)v;
          } else if (EPI == EP_TANHP) {
            v = tanhf(v + aux1[row]);
            ((_Float16*)Cout)[o] = (_Float16)v;
          } else if (EPI == EP_F16) {
            ((_Float16*)Cout)[o] = (_Float16)v;
          } else if (EPI == EP_PART) {
            ((_Float16*)Cout)[(size_t)bz * M * N + o] = (_Float16)v;
          } else {
            ((float*)Cout)[o] = v;
          }
        }
      }
    }
  }
  if (EPI == EP_LOGIT) {
    #pragma unroll
    for (int j = 0; j < FN; ++j) {
      float m = lmax[j];
      m = fmaxf(m, __shfl_xor(m, 16, 64));
      m = fmaxf(m, __shfl_xor(m, 32, 64));
      if ((lane >> 4) == 0) smf[wm * BN + wn * WTN + j * 16 + lr] = m;
    }
    __syncthreads();
    if (tid < BN) {
      int col = nBase + tid;
      if (col < N)
        pmax[(size_t)bx * N + col] = fmaxf(smf[tid], smf[BN + tid]);
    }
  }
}

template<int BM, int BN, int EPI>
__launch_bounds__(256, 4)
__global__ void gemm_nt(const _Float16* __restrict__ A, const _Float16* __restrict__ B,
                        void* __restrict__ Cout, const float* __restrict__ aux1,
                        const float* __restrict__ aux2, float* __restrict__ pmax,
                        int pnchunks, int M, int N, int K, int kLen) {
  __shared__ __align__(16) _Float16 As[BM * 64];
  __shared__ __align__(16) _Float16 Bs[BN * 64];
  gemm_body<BM, BN, EPI>(A, B, Cout, aux1, aux2, pmax, pnchunks, M, N, K, kLen,
                         blockIdx.x, blockIdx.y, blockIdx.z, As, Bs);
}

// ------------- fused logit + full column softmax body (BM == M fits the block) -------------
// Writes E'[j][col] = exp(logit - m_col) / l_col  (1/l folded in — no linv downstream).
template<int BM, int BN>
__device__ __forceinline__ void fused_ls_body(
    const _Float16* __restrict__ A,   // centers [M x K]
    const _Float16* __restrict__ B,   // h_prev  [N x K]
    _Float16* __restrict__ Eout,      // [M x N]
    const float* __restrict__ cn,
    int M, int N, int K, int nBase,
    char* smem, float* redm, float* reds) {
  constexpr int BK = 64;
  constexpr int WTM = BM / 2, WTN = BN / 2;
  constexpr int FM = WTM / 16, FN = WTN / 16;
  constexpr int TLD = BN + 4;                       // padded tile LD (bank stagger)
  _Float16* As = (_Float16*)smem;
  _Float16* Bs = As + BM * BK;
  float* tile = (float*)smem;                       // reused after K-loop
  const int tid  = threadIdx.x;
  const int lane = tid & 63;
  const int wave = tid >> 6;
  const int wm = wave >> 1, wn = wave & 1;
  const int lr    = lane & 15;
  const int kHalf = (lane >> 4) << 3;
  const int srOff  = lane >> 3;
  const int schunk = (lane & 7) ^ srOff;
  floatx4 acc[FM][FN] = {};
  constexpr int AV = BM * BK / (256 * 8);
  constexpr int BV = BN * BK / (256 * 8);

  for (int k0 = 0; k0 < K; k0 += BK) {
    #pragma unroll
    for (int v = 0; v < AV; ++v) {
      int rowBase = v * 32 + wave * 8;
      GLOAD_LDS16(A + (size_t)(rowBase + srOff) * K + k0 + schunk * 8, &As[rowBase * BK]);
    }
    #pragma unroll
    for (int v = 0; v < BV; ++v) {
      int rowBase = v * 32 + wave * 8;
      GLOAD_LDS16(B + (size_t)(nBase + rowBase + srOff) * K + k0 + schunk * 8, &Bs[rowBase * BK]);
    }
    __syncthreads();
    #pragma unroll
    for (int kk = 0; kk < BK; kk += 32) {
      const int q = (kk + kHalf) >> 3;
      half8 af[FM], bfv[FN];
      #pragma unroll
      for (int i = 0; i < FM; ++i) {
        int r = wm * WTM + i * 16 + lr;
        af[i] = *(const half8*)(&As[r * BK + ((q ^ (r & 7)) << 3)]);
      }
      #pragma unroll
      for (int j = 0; j < FN; ++j) {
        int r = wn * WTN + j * 16 + lr;
        bfv[j] = *(const half8*)(&Bs[r * BK + ((q ^ (r & 7)) << 3)]);
      }
      #pragma unroll
      for (int i = 0; i < FM; ++i)
        #pragma unroll
        for (int j = 0; j < FN; ++j)
          acc[i][j] = __builtin_amdgcn_mfma_f32_16x16x32_f16(af[i], bfv[j], acc[i][j], 0, 0, 0);
    }
    __syncthreads();                                // also protects staging->tile reuse
  }

  // logits -> fp32 LDS tile
  const int rBase = (lane >> 4) << 2;
  #pragma unroll
  for (int i = 0; i < FM; ++i)
    #pragma unroll
    for (int j = 0; j < FN; ++j)
      #pragma unroll
      for (int r = 0; r < 4; ++r) {
        int row = wm * WTM + i * 16 + rBase + r;    // row < BM == M
        int col = wn * WTN + j * 16 + lr;
        tile[row * TLD + col] = 0.5f * acc[i][j][r] - 0.25f * cn[row];
      }
  __syncthreads();

  // per-column softmax: P threads per column, rows strided
  constexpr int P = 256 / BN;
  const int c = tid & (BN - 1);
  const int p = tid / BN;
  float m = -1e30f;
  for (int j = p; j < M; j += P) m = fmaxf(m, tile[j * TLD + c]);
  redm[p * BN + c] = m;
  __syncthreads();
  float mf = redm[c];
  #pragma unroll
  for (int q = 1; q < P; ++q) mf = fmaxf(mf, redm[q * BN + c]);
  float s = 0.f;
  for (int j = p; j < M; j += P) {
    float e = __expf(tile[j * TLD + c] - mf);
    tile[j * TLD + c] = e;                          // own cells only
    s += e;
  }
  reds[p * BN + c] = s;
  __syncthreads();
  float l = 0.f;
  #pragma unroll
  for (int q = 0; q < P; ++q) l += reds[q * BN + c];
  const float li = 1.f / l;
  for (int j = p; j < M; j += P)
    Eout[(size_t)j * N + nBase + c] = (_Float16)(tile[j * TLD + c] * li);
}

// ---- level-2 merged launch: fused_ls<256,32> (64 blocks) || TANHP gemm (256 blocks) ----
// Independent consumers of h1b; one launch kills a dispatch gap and overlaps tails.
// Unioned LDS: fused needs 36864(stage/tile) + 2048(red) = 38912; gemm needs 24576.
// (256,4): 4 blocks/CU (4*38912 = 152 KiB <= 160 KiB) — restores gemm-branch TLP.
__launch_bounds__(256, 4)
__global__ void lvl2_merged(const _Float16* __restrict__ cb2,
                            const _Float16* __restrict__ h1b,
                            _Float16* __restrict__ E, const float* __restrict__ cn2,
                            const _Float16* __restrict__ Wb2,
                            _Float16* __restrict__ tT, const float* __restrict__ b2) {
  __shared__ __align__(16) char smem[38912];
  if ((int)blockIdx.x < 64) {
    float* redm = (float*)(smem + 36864);
    float* reds = (float*)(smem + 36864 + 1024);
    fused_ls_body<256, 32>(cb2, h1b, E, cn2, 256, 2048, 1024, blockIdx.x * 32,
                           smem, redm, reds);
  } else {
    int lin = blockIdx.x - 64;   // TANHP grid was dim3(8, 32): bx = lin%8, by = lin/8
    gemm_body<128, 64, EP_TANHP>(Wb2, h1b, tT, b2, nullptr, nullptr, 0,
                                 1024, 2048, 1024, 1024, lin % 8, lin / 8, 0,
                                 (_Float16*)smem, (_Float16*)(smem + 16384));
  }
}

// ---- level-3 merged launch: fused_ls<32,64> (4 blocks) || TANHP gemm (64 blocks) ----
// Unioned LDS: fused needs 12288 + 2048 = 14336; gemm needs 16384. -> 16384.
__launch_bounds__(256, 4)
__global__ void lvl3_merged(const _Float16* __restrict__ cb3,
                            const _Float16* __restrict__ h2b,
                            _Float16* __restrict__ E, const float* __restrict__ cn3,
                            const _Float16* __restrict__ Wb3,
                            _Float16* __restrict__ tT, const float* __restrict__ b3) {
  __shared__ __align__(16) char smem[16384];
  if ((int)blockIdx.x < 4) {
    float* redm = (float*)(smem + 12288);
    float* reds = (float*)(smem + 12288 + 1024);
    fused_ls_body<32, 64>(cb3, h2b, E, cn3, 32, 256, 1024, blockIdx.x * 64,
                          smem, redm, reds);
  } else {
    int lin = blockIdx.x - 4;    // TANHP grid was dim3(16, 4): bx = lin%16, by = lin/16
    gemm_body<64, 64, EP_TANHP>(Wb3, h2b, tT, b3, nullptr, nullptr, 0,
                                1024, 256, 1024, 1024, lin % 16, lin / 16, 0,
                                (_Float16*)smem, (_Float16*)(smem + 8192));
  }
}

extern "C" void kernel_launch(void* const* d_in, const int* in_sizes, int n_in,
                              void* d_out, int out_size, void* d_ws, size_t ws_size,
                              hipStream_t stream) {
  const float* h0 = (const float*)d_in[0];
  const float* c1 = (const float*)d_in[1];
  const float* c2 = (const float*)d_in[2];
  const float* c3 = (const float*)d_in[3];
  const float* W1 = (const float*)d_in[4];
  const float* b1 = (const float*)d_in[5];
  const float* W2 = (const float*)d_in[6];
  const float* b2 = (const float*)d_in[7];
  const float* W3 = (const float*)d_in[8];
  const float* b3 = (const float*)d_in[9];

  const int d = 1024;
  const int N0 = 16384, N1 = 2048, N2 = 256, N3 = 32;

  char* w = (char*)d_ws;
  size_t off = 0;
  auto alloc = [&](size_t bytes) {
    void* p = w + off;
    off += (bytes + 255) & ~(size_t)255;
    return p;
  };
  _Float16* hb  = (_Float16*)alloc((size_t)N0 * d * 2);   // 32 MB
  _Float16* cb1 = (_Float16*)alloc((size_t)N1 * d * 2);
  _Float16* cb2 = (_Float16*)alloc((size_t)N2 * d * 2);
  _Float16* cb3 = (_Float16*)alloc((size_t)N3 * d * 2);
  float* cn1 = (float*)alloc((size_t)N1 * 4);
  float* cn2 = (float*)alloc((size_t)N2 * 4);
  float* cn3 = (float*)alloc((size_t)N3 * 4);
  _Float16* Wb1 = (_Float16*)alloc((size_t)d * d * 2);
  _Float16* Wb2 = (_Float16*)alloc((size_t)d * d * 2);
  _Float16* Wb3 = (_Float16*)alloc((size_t)d * d * 2);
  _Float16* ST = (_Float16*)alloc((size_t)N1 * N0 * 2);   // 64 MB, E overwrites in place
  _Float16* tT = (_Float16*)alloc((size_t)d * N0 * 2);    // 32 MB
  float* pmax = (float*)alloc((size_t)32 * N0 * 4);       // per-block column maxes (L1)
  float* psum = (float*)alloc((size_t)32 * N0 * 4);       // per-chunk column sums (L1)
  _Float16* h1b = (_Float16*)alloc((size_t)N1 * d * 2);
  _Float16* h2b = (_Float16*)alloc((size_t)N2 * d * 2);
  _Float16* Cpart = (_Float16*)alloc((size_t)8 * N1 * d * 2);  // 32 MB fp16 split-K partials
  _Float16* E = ST;
  (void)ws_size; (void)in_sizes; (void)n_in; (void)out_size;

  // ---- prep: one kernel (casts + center norms) ----
  int nh = N0 * d, nw = d * d;
  int castBlocks = cdiv(nh + 3 * nw, 1024);
  prep<<<castBlocks + N1 + N2 + N3, 256, 0, stream>>>(
      h0, W1, W2, W3, c1, c2, c3, hb, Wb1, Wb2, Wb3, cb1, cb2, cb3,
      cn1, cn2, cn3, nh, nw, castBlocks, N1, N2);

  // ---- level 1: h[16384] -> h1[2048] (2-pass softmax; ncur too big for in-block) ----
  gemm_nt<128, 128, EP_LOGIT><<<dim3(16, 128), 256, 0, stream>>>(
      cb1, hb, ST, cn1, nullptr, pmax, 0, N1, N0, d, d);
  colexp_partial<<<dim3(N0 / 1024, cdiv(N1, SM_CHUNK)), 256, 0, stream>>>(
      ST, pmax, psum, 16, N1, N0);
  gemm_nt<128, 128, EP_TANH><<<dim3(8, 128), 256, 0, stream>>>(
      Wb1, hb, tT, b1, psum, nullptr, cdiv(N1, SM_CHUNK), d, N0, d, d);
  gemm_nt<128, 128, EP_PART><<<dim3(16, 8, 8), 256, 0, stream>>>(
      E, tT, Cpart, nullptr, nullptr, nullptr, 0, N1, d, N0, N0 / 8);
  reduce_parts<<<cdiv(N1 * d, 1024), 256, 0, stream>>>(Cpart, h1b, N1 * d, 8);

  // ---- level 2: h1[2048] -> h2[256] (merged: in-block softmax || W2 tanh GEMM) ----
  lvl2_merged<<<64 + 256, 256, 0, stream>>>(cb2, h1b, E, cn2, Wb2, tT, b2);
  // PV L2 direct (1.07 GF): split-K + reduce cost more than they save at this size,
  // and single fp32 accumulation is more accurate than fp16-partial summing.
  gemm_nt<64, 64, EP_F16><<<dim3(4, 16), 256, 0, stream>>>(
      E, tT, h2b, nullptr, nullptr, nullptr, 0, N2, d, N1, N1);

  // ---- level 3: h2[256] -> out[32][1024] fp32 (merged softmax || W3 tanh GEMM) ----
  lvl3_merged<<<4 + 64, 256, 0, stream>>>(cb3, h2b, E, cn3, Wb3, tT, b3);
  gemm_nt<64, 64, EP_F32><<<dim3(1, 16), 256, 0, stream>>>(
      E, tT, d_out, nullptr, nullptr, nullptr, 0, N3, d, N2, N2);
}

// Round 7
// 465.738 us; speedup vs baseline: 1.0275x; 1.0275x over previous
//
#include <hip/hip_runtime.h>
#include <cmath>

typedef _Float16 half8 __attribute__((ext_vector_type(8)));
typedef _Float16 half4v __attribute__((ext_vector_type(4)));
typedef __attribute__((ext_vector_type(4))) float floatx4;

#define GLOAD_LDS16(gp, lp)                                            \
  __builtin_amdgcn_global_load_lds(                                    \
      (const __attribute__((address_space(1))) void*)(gp),             \
      (__attribute__((address_space(3))) void*)(lp), 16, 0, 0)

static inline int cdiv(int a, int b) { return (a + b - 1) / b; }

// SESSION NOTES (do not repeat failed experiments):
//  r1/r2: 256x256 8-phase 1-block/CU gemm8 (T3+T4+T5) regressed (MfmaUtil 33->24%).
//         At K=1024 / 512-block shapes the deep pipeline never fills and 1-block/CU
//         has no TLP cover; gemm_nt's 4-block/CU TLP wins.
//  r3: XCD-chunked block swizzle (T1): FETCH 136->52 MB as predicted but dur 92->107us.
//      Inputs are L3-fit (36 MB); swizzle trades L3-shared hits for per-XCD L2 thrash.
//  r4: stream-K fixup (threadfence+atomic counter) in split-K: L1-PART 90->310us.
//      Device-scope fences invalidate L2 for co-resident blocks. NEVER in hot epilogue.
//  r5: lvl2/lvl3 launch merges of independent kernels: 483->454us (best). Launch-gap
//      reduction is the live lever; GEMMs are at the structure floor (744 TF).
//  r6: 478us but UNMODIFIED kernels (LOGIT, TANH) uniformly +5-6% -> machine-state
//      (clock) noise ~±5%, changes likely neutral. BUT launch_bounds(256,4) on merged
//      kernels caps VGPR=64 < fused_ls_body's ~68 working set (spill risk) - reverted.
//  gemm_nt 128x128 @ 4 blocks/CU = 744 TF here (~82% of the structure's 912 TF
//  ceiling; rest is K=1024 short-loop overhead). Treat as GEMM floor.

// ------- merged prep: cast h0/W1/W2/W3 fp32->fp16, then centers cast + norms -------
__global__ void prep(const float* __restrict__ h0, const float* __restrict__ W1,
                     const float* __restrict__ W2, const float* __restrict__ W3,
                     const float* __restrict__ c1, const float* __restrict__ c2,
                     const float* __restrict__ c3,
                     _Float16* __restrict__ hh, _Float16* __restrict__ Wh1,
                     _Float16* __restrict__ Wh2, _Float16* __restrict__ Wh3,
                     _Float16* __restrict__ cb1, _Float16* __restrict__ cb2,
                     _Float16* __restrict__ cb3,
                     float* __restrict__ cn1, float* __restrict__ cn2,
                     float* __restrict__ cn3,
                     int nh, int nw, int castBlocks, int n1, int n2) {
  int t = threadIdx.x;
  if ((int)blockIdx.x < castBlocks) {
    int gi = (blockIdx.x * 256 + t) * 4;
    const float* src; _Float16* dst; int off;
    if (gi < nh)                { src = h0; dst = hh;  off = gi; }
    else if (gi < nh + nw)      { src = W1; dst = Wh1; off = gi - nh; }
    else if (gi < nh + 2 * nw)  { src = W2; dst = Wh2; off = gi - nh - nw; }
    else if (gi < nh + 3 * nw)  { src = W3; dst = Wh3; off = gi - nh - 2 * nw; }
    else return;
    float4 v = *(const float4*)(src + off);
    half4v o = {(_Float16)v.x, (_Float16)v.y, (_Float16)v.z, (_Float16)v.w};
    *(half4v*)(dst + off) = o;
    return;
  }
  int row = blockIdx.x - castBlocks;
  const float* c; _Float16* cb; float* cn;
  if (row < n1)            { c = c1; cb = cb1; cn = cn1; }
  else if (row < n1 + n2)  { row -= n1; c = c2; cb = cb2; cn = cn2; }
  else                     { row -= n1 + n2; c = c3; cb = cb3; cn = cn3; }
  float4 v = *(const float4*)(c + (size_t)row * 1024 + t * 4);
  half4v o = {(_Float16)v.x, (_Float16)v.y, (_Float16)v.z, (_Float16)v.w};
  *(half4v*)(cb + (size_t)row * 1024 + t * 4) = o;
  float s = v.x * v.x + v.y * v.y + v.z * v.z + v.w * v.w;
  #pragma unroll
  for (int off = 32; off > 0; off >>= 1) s += __shfl_down(s, off, 64);
  __shared__ float ws[4];
  if ((t & 63) == 0) ws[t >> 6] = s;
  __syncthreads();
  if (t == 0) cn[row] = ws[0] + ws[1] + ws[2] + ws[3];
}

// ------------- L1 softmax pass: finalize max from per-block pmax, exp in place, partial sums -------------
#define SM_CHUNK 64
__global__ void colexp_partial(_Float16* __restrict__ ST, const float* __restrict__ pmax,
                               float* __restrict__ psum, int mchunks, int ncur, int nprev) {
  int col = (blockIdx.x * 256 + threadIdx.x) * 4;
  if (col >= nprev) return;
  float m0 = -1e30f, m1 = -1e30f, m2 = -1e30f, m3 = -1e30f;
  for (int k = 0; k < mchunks; ++k) {
    float4 v = *(const float4*)(pmax + (size_t)k * nprev + col);
    m0 = fmaxf(m0, v.x); m1 = fmaxf(m1, v.y); m2 = fmaxf(m2, v.z); m3 = fmaxf(m3, v.w);
  }
  int j0 = blockIdx.y * SM_CHUNK;
  int j1 = min(j0 + SM_CHUNK, ncur);
  float s0 = 0.f, s1 = 0.f, s2 = 0.f, s3 = 0.f;
  for (int j = j0; j < j1; ++j) {
    size_t o = (size_t)j * nprev + col;
    half4v x = *(const half4v*)(ST + o);
    float e0 = __expf((float)x[0] - m0), e1 = __expf((float)x[1] - m1);
    float e2 = __expf((float)x[2] - m2), e3 = __expf((float)x[3] - m3);
    half4v e = {(_Float16)e0, (_Float16)e1, (_Float16)e2, (_Float16)e3};
    *(half4v*)(ST + o) = e;   // in place: same thread reads then writes same elem
    s0 += e0; s1 += e1; s2 += e2; s3 += e3;
  }
  float4 sv = {s0, s1, s2, s3};
  *(float4*)(psum + (size_t)blockIdx.y * nprev + col) = sv;
}

// ---------------- split-K reduce: out_fp16[i] = sum_s part[s][i] (fp16 partials) ----------------
__global__ void reduce_parts(const _Float16* __restrict__ part, _Float16* __restrict__ out,
                             int mn, int S) {
  int i = (blockIdx.x * 256 + threadIdx.x) * 4;
  if (i >= mn) return;
  float a0 = 0.f, a1 = 0.f, a2 = 0.f, a3 = 0.f;
  for (int s = 0; s < S; ++s) {
    half4v v = *(const half4v*)(part + (size_t)s * mn + i);
    a0 += (float)v[0]; a1 += (float)v[1]; a2 += (float)v[2]; a3 += (float)v[3];
  }
  half4v o = {(_Float16)a0, (_Float16)a1, (_Float16)a2, (_Float16)a3};
  *(half4v*)(out + i) = o;
}

enum { EP_LOGIT = 0, EP_TANH = 1, EP_TANHP = 2, EP_F16 = 3, EP_F32 = 4, EP_PART = 5 };

// ---------------- NT fp16 MFMA GEMM body: C[M][N] = A[M][K] * B[N][K]^T ----------------
// global_load_lds (16B) staging, XOR-swizzled LDS (0 bank conflicts). Pristine
// epilogue — no fences, no atomics (see r4 note above).
template<int BM, int BN, int EPI>
__device__ __forceinline__ void gemm_body(
    const _Float16* __restrict__ A, const _Float16* __restrict__ B,
    void* __restrict__ Cout,
    const float* __restrict__ aux1,   // cn[M] or bias[M]
    const float* __restrict__ aux2,   // psum (EP_TANH)
    float* __restrict__ pmax,         // EP_LOGIT out
    int pnchunks,                     // EP_TANH psum chunk count
    int M, int N, int K, int kLen,
    int bx, int by, int bz,
    _Float16* As, _Float16* Bs) {
  constexpr int BK = 64;                 // 128 B/row, unpadded (global_load_lds needs it)
  constexpr int WTM = BM / 2, WTN = BN / 2;
  constexpr int FM = WTM / 16, FN = WTN / 16;
  float* smf = (float*)As;               // aliased: used only after the K-loop
  const int tid  = threadIdx.x;
  const int lane = tid & 63;
  const int wave = tid >> 6;             // 256 threads = 4 waves
  const int wm = wave >> 1, wn = wave & 1;
  const int mBase = bx * BM, nBase = by * BN;
  const int kBase = bz * kLen;
  const int lr    = lane & 15;           // fragment row (A: m, B: n)
  const int kHalf = (lane >> 4) << 3;    // fragment k offset: 0,8,16,24

  const int srOff  = lane >> 3;                        // row within 8-row staging group
  const int schunk = (lane & 7) ^ srOff;               // swizzled global K-chunk
  floatx4 acc[FM][FN] = {};
  constexpr int AV = BM * BK / (256 * 8);
  constexpr int BV = BN * BK / (256 * 8);

  for (int k0 = kBase; k0 < kBase + kLen; k0 += BK) {  // kLen % 64 == 0 everywhere
    #pragma unroll
    for (int v = 0; v < AV; ++v) {
      int rowBase = v * 32 + wave * 8;
      int gm = mBase + rowBase + srOff;
      if (gm >= M) gm = M - 1;                         // clamp: feeds only discarded rows
      GLOAD_LDS16(A + (size_t)gm * K + k0 + schunk * 8, &As[rowBase * BK]);
    }
    #pragma unroll
    for (int v = 0; v < BV; ++v) {
      int rowBase = v * 32 + wave * 8;
      int gn = nBase + rowBase + srOff;
      if (gn >= N) gn = N - 1;
      GLOAD_LDS16(B + (size_t)gn * K + k0 + schunk * 8, &Bs[rowBase * BK]);
    }
    __syncthreads();
    #pragma unroll
    for (int kk = 0; kk < BK; kk += 32) {
      const int q = (kk + kHalf) >> 3;
      half8 af[FM], bfv[FN];
      #pragma unroll
      for (int i = 0; i < FM; ++i) {
        int r = wm * WTM + i * 16 + lr;
        af[i] = *(const half8*)(&As[r * BK + ((q ^ (r & 7)) << 3)]);
      }
      #pragma unroll
      for (int j = 0; j < FN; ++j) {
        int r = wn * WTN + j * 16 + lr;
        bfv[j] = *(const half8*)(&Bs[r * BK + ((q ^ (r & 7)) << 3)]);
      }
      #pragma unroll
      for (int i = 0; i < FM; ++i)
        #pragma unroll
        for (int j = 0; j < FN; ++j)
          acc[i][j] = __builtin_amdgcn_mfma_f32_16x16x32_f16(af[i], bfv[j], acc[i][j], 0, 0, 0);
    }
    __syncthreads();
  }
  // here: all waves past the final barrier; staging LDS is dead -> smf may alias it

  if (EPI == EP_TANH) {                  // linv[col] = 1 / sum_k psum[k][col]
    if (tid < BN) {
      int col = nBase + tid;
      float ssum = 0.f;
      if (col < N)
        for (int k = 0; k < pnchunks; ++k) ssum += aux2[(size_t)k * N + col];
      smf[tid] = 1.f / ssum;
    }
    __syncthreads();
  }

  // epilogue: D row=(lane>>4)*4+r, col=lane&15 (m89-verified mapping)
  const int rBase = (lane >> 4) << 2;
  float lmax[FN];
  #pragma unroll
  for (int j = 0; j < FN; ++j) lmax[j] = -1e30f;
  #pragma unroll
  for (int i = 0; i < FM; ++i) {
    #pragma unroll
    for (int j = 0; j < FN; ++j) {
      #pragma unroll
      for (int r = 0; r < 4; ++r) {
        int row = mBase + wm * WTM + i * 16 + rBase + r;
        int col = nBase + wn * WTN + j * 16 + lr;
        if (row < M && col < N) {
          float v = acc[i][j][r];
          size_t o = (size_t)row * N + col;
          if (EPI == EP_LOGIT) {
            v = 0.5f * v - 0.25f * aux1[row];
            ((_Float16*)Cout)[o] = (_Float16)v;
            lmax[j] = fmaxf(lmax[j], v);
          } else if (EPI == EP_TANH) {
            v = tanhf(v + aux1[row]) * smf[col - nBase];
            ((_Float16*)Cout)[o] = (_Float16)v;
          } else if (EPI == EP_TANHP) {
            v = tanhf(v + aux1[row]);
            ((_Float16*)Cout)[o] = (_Float16)v;
          } else if (EPI == EP_F16) {
            ((_Float16*)Cout)[o] = (_Float16)v;
          } else if (EPI == EP_PART) {
            ((_Float16*)Cout)[(size_t)bz * M * N + o] = (_Float16)v;
          } else {
            ((float*)Cout)[o] = v;
          }
        }
      }
    }
  }
  if (EPI == EP_LOGIT) {
    #pragma unroll
    for (int j = 0; j < FN; ++j) {
      float m = lmax[j];
      m = fmaxf(m, __shfl_xor(m, 16, 64));
      m = fmaxf(m, __shfl_xor(m, 32, 64));
      if ((lane >> 4) == 0) smf[wm * BN + wn * WTN + j * 16 + lr] = m;
    }
    __syncthreads();
    if (tid < BN) {
      int col = nBase + tid;
      if (col < N)
        pmax[(size_t)bx * N + col] = fmaxf(smf[tid], smf[BN + tid]);
    }
  }
}

template<int BM, int BN, int EPI>
__launch_bounds__(256, 4)
__global__ void gemm_nt(const _Float16* __restrict__ A, const _Float16* __restrict__ B,
                        void* __restrict__ Cout, const float* __restrict__ aux1,
                        const float* __restrict__ aux2, float* __restrict__ pmax,
                        int pnchunks, int M, int N, int K, int kLen) {
  __shared__ __align__(16) _Float16 As[BM * 64];
  __shared__ __align__(16) _Float16 Bs[BN * 64];
  gemm_body<BM, BN, EPI>(A, B, Cout, aux1, aux2, pmax, pnchunks, M, N, K, kLen,
                         blockIdx.x, blockIdx.y, blockIdx.z, As, Bs);
}

// ------------- fused logit + full column softmax body (BM == M fits the block) -------------
// Writes E'[j][col] = exp(logit - m_col) / l_col  (1/l folded in — no linv downstream).
template<int BM, int BN>
__device__ __forceinline__ void fused_ls_body(
    const _Float16* __restrict__ A,   // centers [M x K]
    const _Float16* __restrict__ B,   // h_prev  [N x K]
    _Float16* __restrict__ Eout,      // [M x N]
    const float* __restrict__ cn,
    int M, int N, int K, int nBase,
    char* smem, float* redm, float* reds) {
  constexpr int BK = 64;
  constexpr int WTM = BM / 2, WTN = BN / 2;
  constexpr int FM = WTM / 16, FN = WTN / 16;
  constexpr int TLD = BN + 4;                       // padded tile LD (bank stagger)
  _Float16* As = (_Float16*)smem;
  _Float16* Bs = As + BM * BK;
  float* tile = (float*)smem;                       // reused after K-loop
  const int tid  = threadIdx.x;
  const int lane = tid & 63;
  const int wave = tid >> 6;
  const int wm = wave >> 1, wn = wave & 1;
  const int lr    = lane & 15;
  const int kHalf = (lane >> 4) << 3;
  const int srOff  = lane >> 3;
  const int schunk = (lane & 7) ^ srOff;
  floatx4 acc[FM][FN] = {};
  constexpr int AV = BM * BK / (256 * 8);
  constexpr int BV = BN * BK / (256 * 8);

  for (int k0 = 0; k0 < K; k0 += BK) {
    #pragma unroll
    for (int v = 0; v < AV; ++v) {
      int rowBase = v * 32 + wave * 8;
      GLOAD_LDS16(A + (size_t)(rowBase + srOff) * K + k0 + schunk * 8, &As[rowBase * BK]);
    }
    #pragma unroll
    for (int v = 0; v < BV; ++v) {
      int rowBase = v * 32 + wave * 8;
      GLOAD_LDS16(B + (size_t)(nBase + rowBase + srOff) * K + k0 + schunk * 8, &Bs[rowBase * BK]);
    }
    __syncthreads();
    #pragma unroll
    for (int kk = 0; kk < BK; kk += 32) {
      const int q = (kk + kHalf) >> 3;
      half8 af[FM], bfv[FN];
      #pragma unroll
      for (int i = 0; i < FM; ++i) {
        int r = wm * WTM + i * 16 + lr;
        af[i] = *(const half8*)(&As[r * BK + ((q ^ (r & 7)) << 3)]);
      }
      #pragma unroll
      for (int j = 0; j < FN; ++j) {
        int r = wn * WTN + j * 16 + lr;
        bfv[j] = *(const half8*)(&Bs[r * BK + ((q ^ (r & 7)) << 3)]);
      }
      #pragma unroll
      for (int i = 0; i < FM; ++i)
        #pragma unroll
        for (int j = 0; j < FN; ++j)
          acc[i][j] = __builtin_amdgcn_mfma_f32_16x16x32_f16(af[i], bfv[j], acc[i][j], 0, 0, 0);
    }
    __syncthreads();                                // also protects staging->tile reuse
  }

  // logits -> fp32 LDS tile
  const int rBase = (lane >> 4) << 2;
  #pragma unroll
  for (int i = 0; i < FM; ++i)
    #pragma unroll
    for (int j = 0; j < FN; ++j)
      #pragma unroll
      for (int r = 0; r < 4; ++r) {
        int row = wm * WTM + i * 16 + rBase + r;    // row < BM == M
        int col = wn * WTN + j * 16 + lr;
        tile[row * TLD + col] = 0.5f * acc[i][j][r] - 0.25f * cn[row];
      }
  __syncthreads();

  // per-column softmax: P threads per column, rows strided
  constexpr int P = 256 / BN;
  const int c = tid & (BN - 1);
  const int p = tid / BN;
  float m = -1e30f;
  for (int j = p; j < M; j += P) m = fmaxf(m, tile[j * TLD + c]);
  redm[p * BN + c] = m;
  __syncthreads();
  float mf = redm[c];
  #pragma unroll
  for (int q = 1; q < P; ++q) mf = fmaxf(mf, redm[q * BN + c]);
  float s = 0.f;
  for (int j = p; j < M; j += P) {
    float e = __expf(tile[j * TLD + c] - mf);
    tile[j * TLD + c] = e;                          // own cells only
    s += e;
  }
  reds[p * BN + c] = s;
  __syncthreads();
  float l = 0.f;
  #pragma unroll
  for (int q = 0; q < P; ++q) l += reds[q * BN + c];
  const float li = 1.f / l;
  for (int j = p; j < M; j += P)
    Eout[(size_t)j * N + nBase + c] = (_Float16)(tile[j * TLD + c] * li);
}

// ---- level-2 merged launch: fused_ls<256,32> (64 blocks) || TANHP gemm (256 blocks) ----
// Independent consumers of h1b; one launch kills a dispatch gap and overlaps tails.
// Unioned LDS: fused needs 36864(stage/tile) + 2048(red) = 38912; gemm needs 24576.
// (256,2): do NOT raise to (256,4) — caps VGPR at 64 < fused_ls_body's ~68 (r6 note).
__launch_bounds__(256, 2)
__global__ void lvl2_merged(const _Float16* __restrict__ cb2,
                            const _Float16* __restrict__ h1b,
                            _Float16* __restrict__ E, const float* __restrict__ cn2,
                            const _Float16* __restrict__ Wb2,
                            _Float16* __restrict__ tT, const float* __restrict__ b2) {
  __shared__ __align__(16) char smem[38912];
  if ((int)blockIdx.x < 64) {
    float* redm = (float*)(smem + 36864);
    float* reds = (float*)(smem + 36864 + 1024);
    fused_ls_body<256, 32>(cb2, h1b, E, cn2, 256, 2048, 1024, blockIdx.x * 32,
                           smem, redm, reds);
  } else {
    int lin = blockIdx.x - 64;   // TANHP grid was dim3(8, 32): bx = lin%8, by = lin/8
    gemm_body<128, 64, EP_TANHP>(Wb2, h1b, tT, b2, nullptr, nullptr, 0,
                                 1024, 2048, 1024, 1024, lin % 8, lin / 8, 0,
                                 (_Float16*)smem, (_Float16*)(smem + 16384));
  }
}

// ---- level-3 merged launch: fused_ls<32,64> (4 blocks) || TANHP gemm (64 blocks) ----
// Unioned LDS: fused needs 12288 + 2048 = 14336; gemm needs 16384. -> 16384.
__launch_bounds__(256, 2)
__global__ void lvl3_merged(const _Float16* __restrict__ cb3,
                            const _Float16* __restrict__ h2b,
                            _Float16* __restrict__ E, const float* __restrict__ cn3,
                            const _Float16* __restrict__ Wb3,
                            _Float16* __restrict__ tT, const float* __restrict__ b3) {
  __shared__ __align__(16) char smem[16384];
  if ((int)blockIdx.x < 4) {
    float* redm = (float*)(smem + 12288);
    float* reds = (float*)(smem + 12288 + 1024);
    fused_ls_body<32, 64>(cb3, h2b, E, cn3, 32, 256, 1024, blockIdx.x * 64,
                          smem, redm, reds);
  } else {
    int lin = blockIdx.x - 4;    // TANHP grid was dim3(16, 4): bx = lin%16, by = lin/16
    gemm_body<64, 64, EP_TANHP>(Wb3, h2b, tT, b3, nullptr, nullptr, 0,
                                1024, 256, 1024, 1024, lin % 16, lin / 16, 0,
                                (_Float16*)smem, (_Float16*)(smem + 8192));
  }
}

extern "C" void kernel_launch(void* const* d_in, const int* in_sizes, int n_in,
                              void* d_out, int out_size, void* d_ws, size_t ws_size,
                              hipStream_t stream) {
  const float* h0 = (const float*)d_in[0];
  const float* c1 = (const float*)d_in[1];
  const float* c2 = (const float*)d_in[2];
  const float* c3 = (const float*)d_in[3];
  const float* W1 = (const float*)d_in[4];
  const float* b1 = (const float*)d_in[5];
  const float* W2 = (const float*)d_in[6];
  const float* b2 = (const float*)d_in[7];
  const float* W3 = (const float*)d_in[8];
  const float* b3 = (const float*)d_in[9];

  const int d = 1024;
  const int N0 = 16384, N1 = 2048, N2 = 256, N3 = 32;

  char* w = (char*)d_ws;
  size_t off = 0;
  auto alloc = [&](size_t bytes) {
    void* p = w + off;
    off += (bytes + 255) & ~(size_t)255;
    return p;
  };
  _Float16* hb  = (_Float16*)alloc((size_t)N0 * d * 2);   // 32 MB
  _Float16* cb1 = (_Float16*)alloc((size_t)N1 * d * 2);
  _Float16* cb2 = (_Float16*)alloc((size_t)N2 * d * 2);
  _Float16* cb3 = (_Float16*)alloc((size_t)N3 * d * 2);
  float* cn1 = (float*)alloc((size_t)N1 * 4);
  float* cn2 = (float*)alloc((size_t)N2 * 4);
  float* cn3 = (float*)alloc((size_t)N3 * 4);
  _Float16* Wb1 = (_Float16*)alloc((size_t)d * d * 2);
  _Float16* Wb2 = (_Float16*)alloc((size_t)d * d * 2);
  _Float16* Wb3 = (_Float16*)alloc((size_t)d * d * 2);
  _Float16* ST = (_Float16*)alloc((size_t)N1 * N0 * 2);   // 64 MB, E overwrites in place
  _Float16* tT = (_Float16*)alloc((size_t)d * N0 * 2);    // 32 MB
  float* pmax = (float*)alloc((size_t)32 * N0 * 4);       // per-block column maxes (L1)
  float* psum = (float*)alloc((size_t)32 * N0 * 4);       // per-chunk column sums (L1)
  _Float16* h1b = (_Float16*)alloc((size_t)N1 * d * 2);
  _Float16* h2b = (_Float16*)alloc((size_t)N2 * d * 2);
  _Float16* Cpart = (_Float16*)alloc((size_t)8 * N1 * d * 2);  // 32 MB fp16 split-K partials
  _Float16* E = ST;
  (void)ws_size; (void)in_sizes; (void)n_in; (void)out_size;

  // ---- prep: one kernel (casts + center norms) ----
  int nh = N0 * d, nw = d * d;
  int castBlocks = cdiv(nh + 3 * nw, 1024);
  prep<<<castBlocks + N1 + N2 + N3, 256, 0, stream>>>(
      h0, W1, W2, W3, c1, c2, c3, hb, Wb1, Wb2, Wb3, cb1, cb2, cb3,
      cn1, cn2, cn3, nh, nw, castBlocks, N1, N2);

  // ---- level 1: h[16384] -> h1[2048] (2-pass softmax; ncur too big for in-block) ----
  gemm_nt<128, 128, EP_LOGIT><<<dim3(16, 128), 256, 0, stream>>>(
      cb1, hb, ST, cn1, nullptr, pmax, 0, N1, N0, d, d);
  colexp_partial<<<dim3(N0 / 1024, cdiv(N1, SM_CHUNK)), 256, 0, stream>>>(
      ST, pmax, psum, 16, N1, N0);
  gemm_nt<128, 128, EP_TANH><<<dim3(8, 128), 256, 0, stream>>>(
      Wb1, hb, tT, b1, psum, nullptr, cdiv(N1, SM_CHUNK), d, N0, d, d);
  gemm_nt<128, 128, EP_PART><<<dim3(16, 8, 8), 256, 0, stream>>>(
      E, tT, Cpart, nullptr, nullptr, nullptr, 0, N1, d, N0, N0 / 8);
  reduce_parts<<<cdiv(N1 * d, 1024), 256, 0, stream>>>(Cpart, h1b, N1 * d, 8);

  // ---- level 2: h1[2048] -> h2[256] (merged: in-block softmax || W2 tanh GEMM) ----
  lvl2_merged<<<64 + 256, 256, 0, stream>>>(cb2, h1b, E, cn2, Wb2, tT, b2);
  // PV L2 direct (1.07 GF): split-K + reduce cost more than they save at this size,
  // and single fp32 accumulation is more accurate than fp16-partial summing.
  gemm_nt<64, 64, EP_F16><<<dim3(4, 16), 256, 0, stream>>>(
      E, tT, h2b, nullptr, nullptr, nullptr, 0, N2, d, N1, N1);

  // ---- level 3: h2[256] -> out[32][1024] fp32 (merged softmax || W3 tanh GEMM) ----
  lvl3_merged<<<4 + 64, 256, 0, stream>>>(cb3, h2b, E, cn3, Wb3, tT, b3);
  gemm_nt<64, 64, EP_F32><<<dim3(1, 16), 256, 0, stream>>>(
      E, tT, d_out, nullptr, nullptr, nullptr, 0, N3, d, N2, N2);
}

// Round 8
// 455.630 us; speedup vs baseline: 1.0503x; 1.0222x over previous
//
#include <hip/hip_runtime.h>
#include <cmath>

typedef _Float16 half8 __attribute__((ext_vector_type(8)));
typedef _Float16 half4v __attribute__((ext_vector_type(4)));
typedef __attribute__((ext_vector_type(4))) float floatx4;

#define GLOAD_LDS16(gp, lp)                                            \
  __builtin_amdgcn_global_load_lds(                                    \
      (const __attribute__((address_space(1))) void*)(gp),             \
      (__attribute__((address_space(3))) void*)(lp), 16, 0, 0)

static inline int cdiv(int a, int b) { return (a + b - 1) / b; }

// SESSION NOTES (do not repeat failed experiments):
//  r1/r2: 256x256 8-phase 1-block/CU gemm8 (T3+T4+T5) regressed (MfmaUtil 33->24%).
//         At K=1024 / 512-block shapes the deep pipeline never fills and 1-block/CU
//         has no TLP cover; gemm_nt's 4-block/CU TLP wins.
//  r3: XCD-chunked block swizzle (T1): FETCH 136->52 MB as predicted but dur 92->107us.
//      Inputs are L3-fit (36 MB); swizzle trades L3-shared hits for per-XCD L2 thrash.
//  r4: stream-K fixup (threadfence+atomic counter) in split-K: L1-PART 90->310us.
//      Device-scope fences invalidate L2 for co-resident blocks. NEVER in hot epilogue.
//  r5: lvl2/lvl3 launch merges of independent kernels: 483->454us (BEST). Launch-gap
//      reduction is the live lever; GEMMs are at the structure floor (744 TF).
//  r6: uniform +5-6% on unmodified kernels -> machine-state noise; also don't raise
//      merged-kernel launch_bounds to (256,4): caps VGPR=64 < fused_ls ~68 (spills).
//  r7: de-split-K of L2 PV: +12us (64-block K=2048 direct GEMM is latency-bound at
//      0.25 blocks/CU; split-K 512-block + reduce wins despite extra dispatch).
//  gemm_nt 128x128 @ 4 blocks/CU = 744 TF here (~82% of the structure's 912 TF
//  ceiling; rest is K=1024 short-loop overhead). Treat as GEMM floor.

// ------- merged prep: cast h0/W1/W2/W3 fp32->fp16, then centers cast + norms -------
__global__ void prep(const float* __restrict__ h0, const float* __restrict__ W1,
                     const float* __restrict__ W2, const float* __restrict__ W3,
                     const float* __restrict__ c1, const float* __restrict__ c2,
                     const float* __restrict__ c3,
                     _Float16* __restrict__ hh, _Float16* __restrict__ Wh1,
                     _Float16* __restrict__ Wh2, _Float16* __restrict__ Wh3,
                     _Float16* __restrict__ cb1, _Float16* __restrict__ cb2,
                     _Float16* __restrict__ cb3,
                     float* __restrict__ cn1, float* __restrict__ cn2,
                     float* __restrict__ cn3,
                     int nh, int nw, int castBlocks, int n1, int n2) {
  int t = threadIdx.x;
  if ((int)blockIdx.x < castBlocks) {
    int gi = (blockIdx.x * 256 + t) * 4;
    const float* src; _Float16* dst; int off;
    if (gi < nh)                { src = h0; dst = hh;  off = gi; }
    else if (gi < nh + nw)      { src = W1; dst = Wh1; off = gi - nh; }
    else if (gi < nh + 2 * nw)  { src = W2; dst = Wh2; off = gi - nh - nw; }
    else if (gi < nh + 3 * nw)  { src = W3; dst = Wh3; off = gi - nh - 2 * nw; }
    else return;
    float4 v = *(const float4*)(src + off);
    half4v o = {(_Float16)v.x, (_Float16)v.y, (_Float16)v.z, (_Float16)v.w};
    *(half4v*)(dst + off) = o;
    return;
  }
  int row = blockIdx.x - castBlocks;
  const float* c; _Float16* cb; float* cn;
  if (row < n1)            { c = c1; cb = cb1; cn = cn1; }
  else if (row < n1 + n2)  { row -= n1; c = c2; cb = cb2; cn = cn2; }
  else                     { row -= n1 + n2; c = c3; cb = cb3; cn = cn3; }
  float4 v = *(const float4*)(c + (size_t)row * 1024 + t * 4);
  half4v o = {(_Float16)v.x, (_Float16)v.y, (_Float16)v.z, (_Float16)v.w};
  *(half4v*)(cb + (size_t)row * 1024 + t * 4) = o;
  float s = v.x * v.x + v.y * v.y + v.z * v.z + v.w * v.w;
  #pragma unroll
  for (int off = 32; off > 0; off >>= 1) s += __shfl_down(s, off, 64);
  __shared__ float ws[4];
  if ((t & 63) == 0) ws[t >> 6] = s;
  __syncthreads();
  if (t == 0) cn[row] = ws[0] + ws[1] + ws[2] + ws[3];
}

// ------------- L1 softmax pass: finalize max from per-block pmax, exp in place, partial sums -------------
#define SM_CHUNK 64
__global__ void colexp_partial(_Float16* __restrict__ ST, const float* __restrict__ pmax,
                               float* __restrict__ psum, int mchunks, int ncur, int nprev) {
  int col = (blockIdx.x * 256 + threadIdx.x) * 4;
  if (col >= nprev) return;
  float m0 = -1e30f, m1 = -1e30f, m2 = -1e30f, m3 = -1e30f;
  for (int k = 0; k < mchunks; ++k) {
    float4 v = *(const float4*)(pmax + (size_t)k * nprev + col);
    m0 = fmaxf(m0, v.x); m1 = fmaxf(m1, v.y); m2 = fmaxf(m2, v.z); m3 = fmaxf(m3, v.w);
  }
  int j0 = blockIdx.y * SM_CHUNK;
  int j1 = min(j0 + SM_CHUNK, ncur);
  float s0 = 0.f, s1 = 0.f, s2 = 0.f, s3 = 0.f;
  for (int j = j0; j < j1; ++j) {
    size_t o = (size_t)j * nprev + col;
    half4v x = *(const half4v*)(ST + o);
    float e0 = __expf((float)x[0] - m0), e1 = __expf((float)x[1] - m1);
    float e2 = __expf((float)x[2] - m2), e3 = __expf((float)x[3] - m3);
    half4v e = {(_Float16)e0, (_Float16)e1, (_Float16)e2, (_Float16)e3};
    *(half4v*)(ST + o) = e;   // in place: same thread reads then writes same elem
    s0 += e0; s1 += e1; s2 += e2; s3 += e3;
  }
  float4 sv = {s0, s1, s2, s3};
  *(float4*)(psum + (size_t)blockIdx.y * nprev + col) = sv;
}

// ---------------- split-K reduce: out_fp16[i] = sum_s part[s][i] (fp16 partials) ----------------
__global__ void reduce_parts(const _Float16* __restrict__ part, _Float16* __restrict__ out,
                             int mn, int S) {
  int i = (blockIdx.x * 256 + threadIdx.x) * 4;
  if (i >= mn) return;
  float a0 = 0.f, a1 = 0.f, a2 = 0.f, a3 = 0.f;
  for (int s = 0; s < S; ++s) {
    half4v v = *(const half4v*)(part + (size_t)s * mn + i);
    a0 += (float)v[0]; a1 += (float)v[1]; a2 += (float)v[2]; a3 += (float)v[3];
  }
  half4v o = {(_Float16)a0, (_Float16)a1, (_Float16)a2, (_Float16)a3};
  *(half4v*)(out + i) = o;
}

enum { EP_LOGIT = 0, EP_TANH = 1, EP_TANHP = 2, EP_F16 = 3, EP_F32 = 4, EP_PART = 5 };

// ---------------- NT fp16 MFMA GEMM body: C[M][N] = A[M][K] * B[N][K]^T ----------------
// global_load_lds (16B) staging, XOR-swizzled LDS (0 bank conflicts). Pristine
// epilogue — no fences, no atomics (see r4 note above).
template<int BM, int BN, int EPI>
__device__ __forceinline__ void gemm_body(
    const _Float16* __restrict__ A, const _Float16* __restrict__ B,
    void* __restrict__ Cout,
    const float* __restrict__ aux1,   // cn[M] or bias[M]
    const float* __restrict__ aux2,   // psum (EP_TANH)
    float* __restrict__ pmax,         // EP_LOGIT out
    int pnchunks,                     // EP_TANH psum chunk count
    int M, int N, int K, int kLen,
    int bx, int by, int bz,
    _Float16* As, _Float16* Bs) {
  constexpr int BK = 64;                 // 128 B/row, unpadded (global_load_lds needs it)
  constexpr int WTM = BM / 2, WTN = BN / 2;
  constexpr int FM = WTM / 16, FN = WTN / 16;
  float* smf = (float*)As;               // aliased: used only after the K-loop
  const int tid  = threadIdx.x;
  const int lane = tid & 63;
  const int wave = tid >> 6;             // 256 threads = 4 waves
  const int wm = wave >> 1, wn = wave & 1;
  const int mBase = bx * BM, nBase = by * BN;
  const int kBase = bz * kLen;
  const int lr    = lane & 15;           // fragment row (A: m, B: n)
  const int kHalf = (lane >> 4) << 3;    // fragment k offset: 0,8,16,24

  const int srOff  = lane >> 3;                        // row within 8-row staging group
  const int schunk = (lane & 7) ^ srOff;               // swizzled global K-chunk
  floatx4 acc[FM][FN] = {};
  constexpr int AV = BM * BK / (256 * 8);
  constexpr int BV = BN * BK / (256 * 8);

  for (int k0 = kBase; k0 < kBase + kLen; k0 += BK) {  // kLen % 64 == 0 everywhere
    #pragma unroll
    for (int v = 0; v < AV; ++v) {
      int rowBase = v * 32 + wave * 8;
      int gm = mBase + rowBase + srOff;
      if (gm >= M) gm = M - 1;                         // clamp: feeds only discarded rows
      GLOAD_LDS16(A + (size_t)gm * K + k0 + schunk * 8, &As[rowBase * BK]);
    }
    #pragma unroll
    for (int v = 0; v < BV; ++v) {
      int rowBase = v * 32 + wave * 8;
      int gn = nBase + rowBase + srOff;
      if (gn >= N) gn = N - 1;
      GLOAD_LDS16(B + (size_t)gn * K + k0 + schunk * 8, &Bs[rowBase * BK]);
    }
    __syncthreads();
    #pragma unroll
    for (int kk = 0; kk < BK; kk += 32) {
      const int q = (kk + kHalf) >> 3;
      half8 af[FM], bfv[FN];
      #pragma unroll
      for (int i = 0; i < FM; ++i) {
        int r = wm * WTM + i * 16 + lr;
        af[i] = *(const half8*)(&As[r * BK + ((q ^ (r & 7)) << 3)]);
      }
      #pragma unroll
      for (int j = 0; j < FN; ++j) {
        int r = wn * WTN + j * 16 + lr;
        bfv[j] = *(const half8*)(&Bs[r * BK + ((q ^ (r & 7)) << 3)]);
      }
      #pragma unroll
      for (int i = 0; i < FM; ++i)
        #pragma unroll
        for (int j = 0; j < FN; ++j)
          acc[i][j] = __builtin_amdgcn_mfma_f32_16x16x32_f16(af[i], bfv[j], acc[i][j], 0, 0, 0);
    }
    __syncthreads();
  }
  // here: all waves past the final barrier; staging LDS is dead -> smf may alias it

  if (EPI == EP_TANH) {                  // linv[col] = 1 / sum_k psum[k][col]
    if (tid < BN) {
      int col = nBase + tid;
      float ssum = 0.f;
      if (col < N)
        for (int k = 0; k < pnchunks; ++k) ssum += aux2[(size_t)k * N + col];
      smf[tid] = 1.f / ssum;
    }
    __syncthreads();
  }

  // epilogue: D row=(lane>>4)*4+r, col=lane&15 (m89-verified mapping)
  const int rBase = (lane >> 4) << 2;
  float lmax[FN];
  #pragma unroll
  for (int j = 0; j < FN; ++j) lmax[j] = -1e30f;
  #pragma unroll
  for (int i = 0; i < FM; ++i) {
    #pragma unroll
    for (int j = 0; j < FN; ++j) {
      #pragma unroll
      for (int r = 0; r < 4; ++r) {
        int row = mBase + wm * WTM + i * 16 + rBase + r;
        int col = nBase + wn * WTN + j * 16 + lr;
        if (row < M && col < N) {
          float v = acc[i][j][r];
          size_t o = (size_t)row * N + col;
          if (EPI == EP_LOGIT) {
            v = 0.5f * v - 0.25f * aux1[row];
            ((_Float16*)Cout)[o] = (_Float16)v;
            lmax[j] = fmaxf(lmax[j], v);
          } else if (EPI == EP_TANH) {
            v = tanhf(v + aux1[row]) * smf[col - nBase];
            ((_Float16*)Cout)[o] = (_Float16)v;
          } else if (EPI == EP_TANHP) {
            v = tanhf(v + aux1[row]);
            ((_Float16*)Cout)[o] = (_Float16)v;
          } else if (EPI == EP_F16) {
            ((_Float16*)Cout)[o] = (_Float16)v;
          } else if (EPI == EP_PART) {
            ((_Float16*)Cout)[(size_t)bz * M * N + o] = (_Float16)v;
          } else {
            ((float*)Cout)[o] = v;
          }
        }
      }
    }
  }
  if (EPI == EP_LOGIT) {
    #pragma unroll
    for (int j = 0; j < FN; ++j) {
      float m = lmax[j];
      m = fmaxf(m, __shfl_xor(m, 16, 64));
      m = fmaxf(m, __shfl_xor(m, 32, 64));
      if ((lane >> 4) == 0) smf[wm * BN + wn * WTN + j * 16 + lr] = m;
    }
    __syncthreads();
    if (tid < BN) {
      int col = nBase + tid;
      if (col < N)
        pmax[(size_t)bx * N + col] = fmaxf(smf[tid], smf[BN + tid]);
    }
  }
}

template<int BM, int BN, int EPI>
__launch_bounds__(256, 4)
__global__ void gemm_nt(const _Float16* __restrict__ A, const _Float16* __restrict__ B,
                        void* __restrict__ Cout, const float* __restrict__ aux1,
                        const float* __restrict__ aux2, float* __restrict__ pmax,
                        int pnchunks, int M, int N, int K, int kLen) {
  __shared__ __align__(16) _Float16 As[BM * 64];
  __shared__ __align__(16) _Float16 Bs[BN * 64];
  gemm_body<BM, BN, EPI>(A, B, Cout, aux1, aux2, pmax, pnchunks, M, N, K, kLen,
                         blockIdx.x, blockIdx.y, blockIdx.z, As, Bs);
}

// ------------- fused logit + full column softmax body (BM == M fits the block) -------------
// Writes E'[j][col] = exp(logit - m_col) / l_col  (1/l folded in — no linv downstream).
template<int BM, int BN>
__device__ __forceinline__ void fused_ls_body(
    const _Float16* __restrict__ A,   // centers [M x K]
    const _Float16* __restrict__ B,   // h_prev  [N x K]
    _Float16* __restrict__ Eout,      // [M x N]
    const float* __restrict__ cn,
    int M, int N, int K, int nBase,
    char* smem, float* redm, float* reds) {
  constexpr int BK = 64;
  constexpr int WTM = BM / 2, WTN = BN / 2;
  constexpr int FM = WTM / 16, FN = WTN / 16;
  constexpr int TLD = BN + 4;                       // padded tile LD (bank stagger)
  _Float16* As = (_Float16*)smem;
  _Float16* Bs = As + BM * BK;
  float* tile = (float*)smem;                       // reused after K-loop
  const int tid  = threadIdx.x;
  const int lane = tid & 63;
  const int wave = tid >> 6;
  const int wm = wave >> 1, wn = wave & 1;
  const int lr    = lane & 15;
  const int kHalf = (lane >> 4) << 3;
  const int srOff  = lane >> 3;
  const int schunk = (lane & 7) ^ srOff;
  floatx4 acc[FM][FN] = {};
  constexpr int AV = BM * BK / (256 * 8);
  constexpr int BV = BN * BK / (256 * 8);

  for (int k0 = 0; k0 < K; k0 += BK) {
    #pragma unroll
    for (int v = 0; v < AV; ++v) {
      int rowBase = v * 32 + wave * 8;
      GLOAD_LDS16(A + (size_t)(rowBase + srOff) * K + k0 + schunk * 8, &As[rowBase * BK]);
    }
    #pragma unroll
    for (int v = 0; v < BV; ++v) {
      int rowBase = v * 32 + wave * 8;
      GLOAD_LDS16(B + (size_t)(nBase + rowBase + srOff) * K + k0 + schunk * 8, &Bs[rowBase * BK]);
    }
    __syncthreads();
    #pragma unroll
    for (int kk = 0; kk < BK; kk += 32) {
      const int q = (kk + kHalf) >> 3;
      half8 af[FM], bfv[FN];
      #pragma unroll
      for (int i = 0; i < FM; ++i) {
        int r = wm * WTM + i * 16 + lr;
        af[i] = *(const half8*)(&As[r * BK + ((q ^ (r & 7)) << 3)]);
      }
      #pragma unroll
      for (int j = 0; j < FN; ++j) {
        int r = wn * WTN + j * 16 + lr;
        bfv[j] = *(const half8*)(&Bs[r * BK + ((q ^ (r & 7)) << 3)]);
      }
      #pragma unroll
      for (int i = 0; i < FM; ++i)
        #pragma unroll
        for (int j = 0; j < FN; ++j)
          acc[i][j] = __builtin_amdgcn_mfma_f32_16x16x32_f16(af[i], bfv[j], acc[i][j], 0, 0, 0);
    }
    __syncthreads();                                // also protects staging->tile reuse
  }

  // logits -> fp32 LDS tile
  const int rBase = (lane >> 4) << 2;
  #pragma unroll
  for (int i = 0; i < FM; ++i)
    #pragma unroll
    for (int j = 0; j < FN; ++j)
      #pragma unroll
      for (int r = 0; r < 4; ++r) {
        int row = wm * WTM + i * 16 + rBase + r;    // row < BM == M
        int col = wn * WTN + j * 16 + lr;
        tile[row * TLD + col] = 0.5f * acc[i][j][r] - 0.25f * cn[row];
      }
  __syncthreads();

  // per-column softmax: P threads per column, rows strided
  constexpr int P = 256 / BN;
  const int c = tid & (BN - 1);
  const int p = tid / BN;
  float m = -1e30f;
  for (int j = p; j < M; j += P) m = fmaxf(m, tile[j * TLD + c]);
  redm[p * BN + c] = m;
  __syncthreads();
  float mf = redm[c];
  #pragma unroll
  for (int q = 1; q < P; ++q) mf = fmaxf(mf, redm[q * BN + c]);
  float s = 0.f;
  for (int j = p; j < M; j += P) {
    float e = __expf(tile[j * TLD + c] - mf);
    tile[j * TLD + c] = e;                          // own cells only
    s += e;
  }
  reds[p * BN + c] = s;
  __syncthreads();
  float l = 0.f;
  #pragma unroll
  for (int q = 0; q < P; ++q) l += reds[q * BN + c];
  const float li = 1.f / l;
  for (int j = p; j < M; j += P)
    Eout[(size_t)j * N + nBase + c] = (_Float16)(tile[j * TLD + c] * li);
}

// ---- level-2 merged launch: fused_ls<256,32> (64 blocks) || TANHP gemm (256 blocks) ----
// Independent consumers of h1b; one launch kills a dispatch gap and overlaps tails.
// Unioned LDS: fused needs 36864(stage/tile) + 2048(red) = 38912; gemm needs 24576.
// (256,2): do NOT raise to (256,4) — caps VGPR=64 < fused_ls_body's ~68 (r6 note).
__launch_bounds__(256, 2)
__global__ void lvl2_merged(const _Float16* __restrict__ cb2,
                            const _Float16* __restrict__ h1b,
                            _Float16* __restrict__ E, const float* __restrict__ cn2,
                            const _Float16* __restrict__ Wb2,
                            _Float16* __restrict__ tT, const float* __restrict__ b2) {
  __shared__ __align__(16) char smem[38912];
  if ((int)blockIdx.x < 64) {
    float* redm = (float*)(smem + 36864);
    float* reds = (float*)(smem + 36864 + 1024);
    fused_ls_body<256, 32>(cb2, h1b, E, cn2, 256, 2048, 1024, blockIdx.x * 32,
                           smem, redm, reds);
  } else {
    int lin = blockIdx.x - 64;   // TANHP grid was dim3(8, 32): bx = lin%8, by = lin/8
    gemm_body<128, 64, EP_TANHP>(Wb2, h1b, tT, b2, nullptr, nullptr, 0,
                                 1024, 2048, 1024, 1024, lin % 8, lin / 8, 0,
                                 (_Float16*)smem, (_Float16*)(smem + 16384));
  }
}

// ---- level-3 merged launch: fused_ls<32,64> (4 blocks) || TANHP gemm (64 blocks) ----
// Unioned LDS: fused needs 12288 + 2048 = 14336; gemm needs 16384. -> 16384.
__launch_bounds__(256, 2)
__global__ void lvl3_merged(const _Float16* __restrict__ cb3,
                            const _Float16* __restrict__ h2b,
                            _Float16* __restrict__ E, const float* __restrict__ cn3,
                            const _Float16* __restrict__ Wb3,
                            _Float16* __restrict__ tT, const float* __restrict__ b3) {
  __shared__ __align__(16) char smem[16384];
  if ((int)blockIdx.x < 4) {
    float* redm = (float*)(smem + 12288);
    float* reds = (float*)(smem + 12288 + 1024);
    fused_ls_body<32, 64>(cb3, h2b, E, cn3, 32, 256, 1024, blockIdx.x * 64,
                          smem, redm, reds);
  } else {
    int lin = blockIdx.x - 4;    // TANHP grid was dim3(16, 4): bx = lin%16, by = lin/16
    gemm_body<64, 64, EP_TANHP>(Wb3, h2b, tT, b3, nullptr, nullptr, 0,
                                1024, 256, 1024, 1024, lin % 16, lin / 16, 0,
                                (_Float16*)smem, (_Float16*)(smem + 8192));
  }
}

extern "C" void kernel_launch(void* const* d_in, const int* in_sizes, int n_in,
                              void* d_out, int out_size, void* d_ws, size_t ws_size,
                              hipStream_t stream) {
  const float* h0 = (const float*)d_in[0];
  const float* c1 = (const float*)d_in[1];
  const float* c2 = (const float*)d_in[2];
  const float* c3 = (const float*)d_in[3];
  const float* W1 = (const float*)d_in[4];
  const float* b1 = (const float*)d_in[5];
  const float* W2 = (const float*)d_in[6];
  const float* b2 = (const float*)d_in[7];
  const float* W3 = (const float*)d_in[8];
  const float* b3 = (const float*)d_in[9];

  const int d = 1024;
  const int N0 = 16384, N1 = 2048, N2 = 256, N3 = 32;

  char* w = (char*)d_ws;
  size_t off = 0;
  auto alloc = [&](size_t bytes) {
    void* p = w + off;
    off += (bytes + 255) & ~(size_t)255;
    return p;
  };
  _Float16* hb  = (_Float16*)alloc((size_t)N0 * d * 2);   // 32 MB
  _Float16* cb1 = (_Float16*)alloc((size_t)N1 * d * 2);
  _Float16* cb2 = (_Float16*)alloc((size_t)N2 * d * 2);
  _Float16* cb3 = (_Float16*)alloc((size_t)N3 * d * 2);
  float* cn1 = (float*)alloc((size_t)N1 * 4);
  float* cn2 = (float*)alloc((size_t)N2 * 4);
  float* cn3 = (float*)alloc((size_t)N3 * 4);
  _Float16* Wb1 = (_Float16*)alloc((size_t)d * d * 2);
  _Float16* Wb2 = (_Float16*)alloc((size_t)d * d * 2);
  _Float16* Wb3 = (_Float16*)alloc((size_t)d * d * 2);
  _Float16* ST = (_Float16*)alloc((size_t)N1 * N0 * 2);   // 64 MB, E overwrites in place
  _Float16* tT = (_Float16*)alloc((size_t)d * N0 * 2);    // 32 MB
  float* pmax = (float*)alloc((size_t)32 * N0 * 4);       // per-block column maxes (L1)
  float* psum = (float*)alloc((size_t)32 * N0 * 4);       // per-chunk column sums (L1)
  _Float16* h1b = (_Float16*)alloc((size_t)N1 * d * 2);
  _Float16* h2b = (_Float16*)alloc((size_t)N2 * d * 2);
  _Float16* Cpart = (_Float16*)alloc((size_t)8 * N1 * d * 2);  // 32 MB fp16 split-K partials
  _Float16* E = ST;
  (void)ws_size; (void)in_sizes; (void)n_in; (void)out_size;

  // ---- prep: one kernel (casts + center norms) ----
  int nh = N0 * d, nw = d * d;
  int castBlocks = cdiv(nh + 3 * nw, 1024);
  prep<<<castBlocks + N1 + N2 + N3, 256, 0, stream>>>(
      h0, W1, W2, W3, c1, c2, c3, hb, Wb1, Wb2, Wb3, cb1, cb2, cb3,
      cn1, cn2, cn3, nh, nw, castBlocks, N1, N2);

  // ---- level 1: h[16384] -> h1[2048] (2-pass softmax; ncur too big for in-block) ----
  gemm_nt<128, 128, EP_LOGIT><<<dim3(16, 128), 256, 0, stream>>>(
      cb1, hb, ST, cn1, nullptr, pmax, 0, N1, N0, d, d);
  colexp_partial<<<dim3(N0 / 1024, cdiv(N1, SM_CHUNK)), 256, 0, stream>>>(
      ST, pmax, psum, 16, N1, N0);
  gemm_nt<128, 128, EP_TANH><<<dim3(8, 128), 256, 0, stream>>>(
      Wb1, hb, tT, b1, psum, nullptr, cdiv(N1, SM_CHUNK), d, N0, d, d);
  gemm_nt<128, 128, EP_PART><<<dim3(16, 8, 8), 256, 0, stream>>>(
      E, tT, Cpart, nullptr, nullptr, nullptr, 0, N1, d, N0, N0 / 8);
  reduce_parts<<<cdiv(N1 * d, 1024), 256, 0, stream>>>(Cpart, h1b, N1 * d, 8);

  // ---- level 2: h1[2048] -> h2[256] (merged: in-block softmax || W2 tanh GEMM) ----
  lvl2_merged<<<64 + 256, 256, 0, stream>>>(cb2, h1b, E, cn2, Wb2, tT, b2);
  gemm_nt<64, 64, EP_PART><<<dim3(4, 16, 8), 256, 0, stream>>>(
      E, tT, Cpart, nullptr, nullptr, nullptr, 0, N2, d, N1, N1 / 8);
  reduce_parts<<<cdiv(N2 * d, 1024), 256, 0, stream>>>(Cpart, h2b, N2 * d, 8);

  // ---- level 3: h2[256] -> out[32][1024] fp32 (merged softmax || W3 tanh GEMM) ----
  lvl3_merged<<<4 + 64, 256, 0, stream>>>(cb3, h2b, E, cn3, Wb3, tT, b3);
  gemm_nt<64, 64, EP_F32><<<dim3(1, 16), 256, 0, stream>>>(
      E, tT, d_out, nullptr, nullptr, nullptr, 0, N3, d, N2, N2);
}

// Round 9
// 426.811 us; speedup vs baseline: 1.1212x; 1.0675x over previous
//
#include <hip/hip_runtime.h>
#include <cmath>

typedef _Float16 half8 __attribute__((ext_vector_type(8)));
typedef _Float16 half4v __attribute__((ext_vector_type(4)));
typedef __attribute__((ext_vector_type(4))) float floatx4;

#define GLOAD_LDS16(gp, lp)                                            \
  __builtin_amdgcn_global_load_lds(                                    \
      (const __attribute__((address_space(1))) void*)(gp),             \
      (__attribute__((address_space(3))) void*)(lp), 16, 0, 0)

static inline int cdiv(int a, int b) { return (a + b - 1) / b; }

// SESSION NOTES (do not repeat failed experiments):
//  r1/r2: 256x256 8-phase 1-block/CU gemm8 (T3+T4+T5) regressed (MfmaUtil 33->24%).
//         At K=1024 / 512-block shapes the deep pipeline never fills; 4-block/CU TLP wins.
//  r3: XCD-chunked block swizzle (T1): FETCH 136->52 MB but dur 92->107us. Inputs are
//      L3-fit (36 MB); swizzle trades L3-shared hits for per-XCD L2 thrash.
//  r4: stream-K fixup (threadfence+atomic) in split-K: 90->310us. Device-scope fences
//      invalidate L2 for co-resident blocks. NEVER in a hot epilogue.
//  r5: lvl2/lvl3 launch merges of independent kernels: 483->454us (BEST baseline).
//  r6: machine-state noise can be ±5% whole-run (check unmodified-kernel durs);
//      don't raise merged-kernel launch_bounds to (256,4): VGPR 64 < fused_ls ~68.
//  r7: de-split-K of L2 PV: +12us (64 blocks @ K=2048 is latency-bound at 0.25
//      blocks/CU; split-K + reduce wins despite the extra dispatch).
//  r8: EP_TANH runs at 337 TF vs LOGIT 716 TF (same B-sweep, half the FLOPs) ->
//      r9 merges both into EP_LT over A=[cb1;Wb1], with 1/l moved to tscale pass.
//  gemm_nt 128x128 @ 4 blocks/CU = 744 TF floor (~82% of the structure's 912 TF).

// ------- merged prep: cast h0/W1/W2/W3 fp32->fp16, then centers cast + norms -------
__global__ void prep(const float* __restrict__ h0, const float* __restrict__ W1,
                     const float* __restrict__ W2, const float* __restrict__ W3,
                     const float* __restrict__ c1, const float* __restrict__ c2,
                     const float* __restrict__ c3,
                     _Float16* __restrict__ hh, _Float16* __restrict__ Wh1,
                     _Float16* __restrict__ Wh2, _Float16* __restrict__ Wh3,
                     _Float16* __restrict__ cb1, _Float16* __restrict__ cb2,
                     _Float16* __restrict__ cb3,
                     float* __restrict__ cn1, float* __restrict__ cn2,
                     float* __restrict__ cn3,
                     int nh, int nw, int castBlocks, int n1, int n2) {
  int t = threadIdx.x;
  if ((int)blockIdx.x < castBlocks) {
    int gi = (blockIdx.x * 256 + t) * 4;
    const float* src; _Float16* dst; int off;
    if (gi < nh)                { src = h0; dst = hh;  off = gi; }
    else if (gi < nh + nw)      { src = W1; dst = Wh1; off = gi - nh; }
    else if (gi < nh + 2 * nw)  { src = W2; dst = Wh2; off = gi - nh - nw; }
    else if (gi < nh + 3 * nw)  { src = W3; dst = Wh3; off = gi - nh - 2 * nw; }
    else return;
    float4 v = *(const float4*)(src + off);
    half4v o = {(_Float16)v.x, (_Float16)v.y, (_Float16)v.z, (_Float16)v.w};
    *(half4v*)(dst + off) = o;
    return;
  }
  int row = blockIdx.x - castBlocks;
  const float* c; _Float16* cb; float* cn;
  if (row < n1)            { c = c1; cb = cb1; cn = cn1; }
  else if (row < n1 + n2)  { row -= n1; c = c2; cb = cb2; cn = cn2; }
  else                     { row -= n1 + n2; c = c3; cb = cb3; cn = cn3; }
  float4 v = *(const float4*)(c + (size_t)row * 1024 + t * 4);
  half4v o = {(_Float16)v.x, (_Float16)v.y, (_Float16)v.z, (_Float16)v.w};
  *(half4v*)(cb + (size_t)row * 1024 + t * 4) = o;
  float s = v.x * v.x + v.y * v.y + v.z * v.z + v.w * v.w;
  #pragma unroll
  for (int off = 32; off > 0; off >>= 1) s += __shfl_down(s, off, 64);
  __shared__ float ws[4];
  if ((t & 63) == 0) ws[t >> 6] = s;
  __syncthreads();
  if (t == 0) cn[row] = ws[0] + ws[1] + ws[2] + ws[3];
}

// ------------- L1 softmax pass: finalize max from per-block pmax, exp in place, partial sums -------------
#define SM_CHUNK 64
__global__ void colexp_partial(_Float16* __restrict__ ST, const float* __restrict__ pmax,
                               float* __restrict__ psum, int mchunks, int ncur, int nprev) {
  int col = (blockIdx.x * 256 + threadIdx.x) * 4;
  if (col >= nprev) return;
  float m0 = -1e30f, m1 = -1e30f, m2 = -1e30f, m3 = -1e30f;
  for (int k = 0; k < mchunks; ++k) {
    float4 v = *(const float4*)(pmax + (size_t)k * nprev + col);
    m0 = fmaxf(m0, v.x); m1 = fmaxf(m1, v.y); m2 = fmaxf(m2, v.z); m3 = fmaxf(m3, v.w);
  }
  int j0 = blockIdx.y * SM_CHUNK;
  int j1 = min(j0 + SM_CHUNK, ncur);
  float s0 = 0.f, s1 = 0.f, s2 = 0.f, s3 = 0.f;
  for (int j = j0; j < j1; ++j) {
    size_t o = (size_t)j * nprev + col;
    half4v x = *(const half4v*)(ST + o);
    float e0 = __expf((float)x[0] - m0), e1 = __expf((float)x[1] - m1);
    float e2 = __expf((float)x[2] - m2), e3 = __expf((float)x[3] - m3);
    half4v e = {(_Float16)e0, (_Float16)e1, (_Float16)e2, (_Float16)e3};
    *(half4v*)(ST + o) = e;   // in place: same thread reads then writes same elem
    s0 += e0; s1 += e1; s2 += e2; s3 += e3;
  }
  float4 sv = {s0, s1, s2, s3};
  *(float4*)(psum + (size_t)blockIdx.y * nprev + col) = sv;
}

// ---- tscale: tT[r][c] *= 1/l_c where l_c = sum_k psum[k][c] (folds softmax denom) ----
// grid (N0/256, nrows/64), 256 thr. Coalesced half4 sweeps; linv staged in LDS.
__global__ void tscale(_Float16* __restrict__ tT, const float* __restrict__ psum,
                       int pnchunks, int N0) {
  __shared__ float linv[256];
  const int t = threadIdx.x;
  const int c0 = blockIdx.x * 256;
  float s = 0.f;
  for (int k = 0; k < pnchunks; ++k) s += psum[(size_t)k * N0 + c0 + t];
  linv[t] = 1.f / s;
  __syncthreads();
  const int cc = (t & 63) * 4;
  const float4 li = *(const float4*)&linv[cc];
  const int r0 = blockIdx.y * 64 + (t >> 6) * 16;
  for (int r = r0; r < r0 + 16; ++r) {
    size_t o = (size_t)r * N0 + c0 + cc;
    half4v v = *(const half4v*)(tT + o);
    half4v ov = {(_Float16)((float)v[0] * li.x), (_Float16)((float)v[1] * li.y),
                 (_Float16)((float)v[2] * li.z), (_Float16)((float)v[3] * li.w)};
    *(half4v*)(tT + o) = ov;
  }
}

// ---------------- split-K reduce: out_fp16[i] = sum_s part[s][i] (fp16 partials) ----------------
__global__ void reduce_parts(const _Float16* __restrict__ part, _Float16* __restrict__ out,
                             int mn, int S) {
  int i = (blockIdx.x * 256 + threadIdx.x) * 4;
  if (i >= mn) return;
  float a0 = 0.f, a1 = 0.f, a2 = 0.f, a3 = 0.f;
  for (int s = 0; s < S; ++s) {
    half4v v = *(const half4v*)(part + (size_t)s * mn + i);
    a0 += (float)v[0]; a1 += (float)v[1]; a2 += (float)v[2]; a3 += (float)v[3];
  }
  half4v o = {(_Float16)a0, (_Float16)a1, (_Float16)a2, (_Float16)a3};
  *(half4v*)(out + i) = o;
}

enum { EP_LOGIT = 0, EP_TANH = 1, EP_TANHP = 2, EP_F16 = 3, EP_F32 = 4, EP_PART = 5,
       EP_LT = 6 };

// ---------------- NT fp16 MFMA GEMM body: C[M][N] = A[M][K] * B[N][K]^T ----------------
// global_load_lds (16B) staging, XOR-swizzled LDS (0 bank conflicts). Pristine
// epilogue — no fences, no atomics (r4 note).
// EP_LT: A = [centers(Ms rows); W(M-Ms rows)], Ms = pnchunks arg. Blocks with
// mBase<Ms run the LOGIT epilogue (Cout=ST + pmax); others write tanh(v+aux2[row-Ms])
// to Cout2. One B-sweep for both GEMMs (r8 finding: separate TANH ran at half eff.).
template<int BM, int BN, int EPI>
__device__ __forceinline__ void gemm_body(
    const _Float16* __restrict__ A, const _Float16* __restrict__ B,
    void* __restrict__ Cout,
    const float* __restrict__ aux1,   // cn[M] or bias[M]
    const float* __restrict__ aux2,   // psum (EP_TANH) / bias (EP_LT)
    float* __restrict__ pmax,         // EP_LOGIT/EP_LT out
    int pnchunks,                     // EP_TANH psum chunks / EP_LT row split Ms
    int M, int N, int K, int kLen,
    int bx, int by, int bz,
    void* __restrict__ Cout2,         // EP_LT tanh output
    _Float16* As, _Float16* Bs) {
  constexpr int BK = 64;                 // 128 B/row, unpadded (global_load_lds needs it)
  constexpr int WTM = BM / 2, WTN = BN / 2;
  constexpr int FM = WTM / 16, FN = WTN / 16;
  float* smf = (float*)As;               // aliased: used only after the K-loop
  const int tid  = threadIdx.x;
  const int lane = tid & 63;
  const int wave = tid >> 6;             // 256 threads = 4 waves
  const int wm = wave >> 1, wn = wave & 1;
  const int mBase = bx * BM, nBase = by * BN;
  const int kBase = bz * kLen;
  const int lr    = lane & 15;           // fragment row (A: m, B: n)
  const int kHalf = (lane >> 4) << 3;    // fragment k offset: 0,8,16,24

  const int srOff  = lane >> 3;                        // row within 8-row staging group
  const int schunk = (lane & 7) ^ srOff;               // swizzled global K-chunk
  floatx4 acc[FM][FN] = {};
  constexpr int AV = BM * BK / (256 * 8);
  constexpr int BV = BN * BK / (256 * 8);

  for (int k0 = kBase; k0 < kBase + kLen; k0 += BK) {  // kLen % 64 == 0 everywhere
    #pragma unroll
    for (int v = 0; v < AV; ++v) {
      int rowBase = v * 32 + wave * 8;
      int gm = mBase + rowBase + srOff;
      if (gm >= M) gm = M - 1;                         // clamp: feeds only discarded rows
      GLOAD_LDS16(A + (size_t)gm * K + k0 + schunk * 8, &As[rowBase * BK]);
    }
    #pragma unroll
    for (int v = 0; v < BV; ++v) {
      int rowBase = v * 32 + wave * 8;
      int gn = nBase + rowBase + srOff;
      if (gn >= N) gn = N - 1;
      GLOAD_LDS16(B + (size_t)gn * K + k0 + schunk * 8, &Bs[rowBase * BK]);
    }
    __syncthreads();
    #pragma unroll
    for (int kk = 0; kk < BK; kk += 32) {
      const int q = (kk + kHalf) >> 3;
      half8 af[FM], bfv[FN];
      #pragma unroll
      for (int i = 0; i < FM; ++i) {
        int r = wm * WTM + i * 16 + lr;
        af[i] = *(const half8*)(&As[r * BK + ((q ^ (r & 7)) << 3)]);
      }
      #pragma unroll
      for (int j = 0; j < FN; ++j) {
        int r = wn * WTN + j * 16 + lr;
        bfv[j] = *(const half8*)(&Bs[r * BK + ((q ^ (r & 7)) << 3)]);
      }
      #pragma unroll
      for (int i = 0; i < FM; ++i)
        #pragma unroll
        for (int j = 0; j < FN; ++j)
          acc[i][j] = __builtin_amdgcn_mfma_f32_16x16x32_f16(af[i], bfv[j], acc[i][j], 0, 0, 0);
    }
    __syncthreads();
  }
  // here: all waves past the final barrier; staging LDS is dead -> smf may alias it

  if (EPI == EP_TANH) {                  // linv[col] = 1 / sum_k psum[k][col]
    if (tid < BN) {
      int col = nBase + tid;
      float ssum = 0.f;
      if (col < N)
        for (int k = 0; k < pnchunks; ++k) ssum += aux2[(size_t)k * N + col];
      smf[tid] = 1.f / ssum;
    }
    __syncthreads();
  }

  // epilogue: D row=(lane>>4)*4+r, col=lane&15 (m89-verified mapping)
  const int rBase = (lane >> 4) << 2;
  if (EPI == EP_LT) {
    const int Ms = pnchunks;                       // row split: [0,Ms) logit, rest tanh
    if (mBase < Ms) {
      float lmax[FN];
      #pragma unroll
      for (int j = 0; j < FN; ++j) lmax[j] = -1e30f;
      #pragma unroll
      for (int i = 0; i < FM; ++i)
        #pragma unroll
        for (int j = 0; j < FN; ++j)
          #pragma unroll
          for (int r = 0; r < 4; ++r) {
            int row = mBase + wm * WTM + i * 16 + rBase + r;
            int col = nBase + wn * WTN + j * 16 + lr;
            float v = 0.5f * acc[i][j][r] - 0.25f * aux1[row];
            ((_Float16*)Cout)[(size_t)row * N + col] = (_Float16)v;
            lmax[j] = fmaxf(lmax[j], v);
          }
      #pragma unroll
      for (int j = 0; j < FN; ++j) {
        float m = lmax[j];
        m = fmaxf(m, __shfl_xor(m, 16, 64));
        m = fmaxf(m, __shfl_xor(m, 32, 64));
        if ((lane >> 4) == 0) smf[wm * BN + wn * WTN + j * 16 + lr] = m;
      }
      __syncthreads();
      if (tid < BN)
        pmax[(size_t)bx * N + nBase + tid] = fmaxf(smf[tid], smf[BN + tid]);
    } else {
      _Float16* t2 = (_Float16*)Cout2;
      #pragma unroll
      for (int i = 0; i < FM; ++i)
        #pragma unroll
        for (int j = 0; j < FN; ++j)
          #pragma unroll
          for (int r = 0; r < 4; ++r) {
            int row = mBase - Ms + wm * WTM + i * 16 + rBase + r;
            int col = nBase + wn * WTN + j * 16 + lr;
            float v = tanhf(acc[i][j][r] + aux2[row]);
            t2[(size_t)row * N + col] = (_Float16)v;
          }
    }
    return;
  }
  float lmax[FN];
  #pragma unroll
  for (int j = 0; j < FN; ++j) lmax[j] = -1e30f;
  #pragma unroll
  for (int i = 0; i < FM; ++i) {
    #pragma unroll
    for (int j = 0; j < FN; ++j) {
      #pragma unroll
      for (int r = 0; r < 4; ++r) {
        int row = mBase + wm * WTM + i * 16 + rBase + r;
        int col = nBase + wn * WTN + j * 16 + lr;
        if (row < M && col < N) {
          float v = acc[i][j][r];
          size_t o = (size_t)row * N + col;
          if (EPI == EP_LOGIT) {
            v = 0.5f * v - 0.25f * aux1[row];
            ((_Float16*)Cout)[o] = (_Float16)v;
            lmax[j] = fmaxf(lmax[j], v);
          } else if (EPI == EP_TANH) {
            v = tanhf(v + aux1[row]) * smf[col - nBase];
            ((_Float16*)Cout)[o] = (_Float16)v;
          } else if (EPI == EP_TANHP) {
            v = tanhf(v + aux1[row]);
            ((_Float16*)Cout)[o] = (_Float16)v;
          } else if (EPI == EP_F16) {
            ((_Float16*)Cout)[o] = (_Float16)v;
          } else if (EPI == EP_PART) {
            ((_Float16*)Cout)[(size_t)bz * M * N + o] = (_Float16)v;
          } else {
            ((float*)Cout)[o] = v;
          }
        }
      }
    }
  }
  if (EPI == EP_LOGIT) {
    #pragma unroll
    for (int j = 0; j < FN; ++j) {
      float m = lmax[j];
      m = fmaxf(m, __shfl_xor(m, 16, 64));
      m = fmaxf(m, __shfl_xor(m, 32, 64));
      if ((lane >> 4) == 0) smf[wm * BN + wn * WTN + j * 16 + lr] = m;
    }
    __syncthreads();
    if (tid < BN) {
      int col = nBase + tid;
      if (col < N)
        pmax[(size_t)bx * N + col] = fmaxf(smf[tid], smf[BN + tid]);
    }
  }
}

template<int BM, int BN, int EPI>
__launch_bounds__(256, 4)
__global__ void gemm_nt(const _Float16* __restrict__ A, const _Float16* __restrict__ B,
                        void* __restrict__ Cout, const float* __restrict__ aux1,
                        const float* __restrict__ aux2, float* __restrict__ pmax,
                        int pnchunks, int M, int N, int K, int kLen,
                        void* __restrict__ Cout2) {
  __shared__ __align__(16) _Float16 As[BM * 64];
  __shared__ __align__(16) _Float16 Bs[BN * 64];
  gemm_body<BM, BN, EPI>(A, B, Cout, aux1, aux2, pmax, pnchunks, M, N, K, kLen,
                         blockIdx.x, blockIdx.y, blockIdx.z, Cout2, As, Bs);
}

// ------------- fused logit + full column softmax body (BM == M fits the block) -------------
// Writes E'[j][col] = exp(logit - m_col) / l_col  (1/l folded in — no linv downstream).
template<int BM, int BN>
__device__ __forceinline__ void fused_ls_body(
    const _Float16* __restrict__ A,   // centers [M x K]
    const _Float16* __restrict__ B,   // h_prev  [N x K]
    _Float16* __restrict__ Eout,      // [M x N]
    const float* __restrict__ cn,
    int M, int N, int K, int nBase,
    char* smem, float* redm, float* reds) {
  constexpr int BK = 64;
  constexpr int WTM = BM / 2, WTN = BN / 2;
  constexpr int FM = WTM / 16, FN = WTN / 16;
  constexpr int TLD = BN + 4;                       // padded tile LD (bank stagger)
  _Float16* As = (_Float16*)smem;
  _Float16* Bs = As + BM * BK;
  float* tile = (float*)smem;                       // reused after K-loop
  const int tid  = threadIdx.x;
  const int lane = tid & 63;
  const int wave = tid >> 6;
  const int wm = wave >> 1, wn = wave & 1;
  const int lr    = lane & 15;
  const int kHalf = (lane >> 4) << 3;
  const int srOff  = lane >> 3;
  const int schunk = (lane & 7) ^ srOff;
  floatx4 acc[FM][FN] = {};
  constexpr int AV = BM * BK / (256 * 8);
  constexpr int BV = BN * BK / (256 * 8);

  for (int k0 = 0; k0 < K; k0 += BK) {
    #pragma unroll
    for (int v = 0; v < AV; ++v) {
      int rowBase = v * 32 + wave * 8;
      GLOAD_LDS16(A + (size_t)(rowBase + srOff) * K + k0 + schunk * 8, &As[rowBase * BK]);
    }
    #pragma unroll
    for (int v = 0; v < BV; ++v) {
      int rowBase = v * 32 + wave * 8;
      GLOAD_LDS16(B + (size_t)(nBase + rowBase + srOff) * K + k0 + schunk * 8, &Bs[rowBase * BK]);
    }
    __syncthreads();
    #pragma unroll
    for (int kk = 0; kk < BK; kk += 32) {
      const int q = (kk + kHalf) >> 3;
      half8 af[FM], bfv[FN];
      #pragma unroll
      for (int i = 0; i < FM; ++i) {
        int r = wm * WTM + i * 16 + lr;
        af[i] = *(const half8*)(&As[r * BK + ((q ^ (r & 7)) << 3)]);
      }
      #pragma unroll
      for (int j = 0; j < FN; ++j) {
        int r = wn * WTN + j * 16 + lr;
        bfv[j] = *(const half8*)(&Bs[r * BK + ((q ^ (r & 7)) << 3)]);
      }
      #pragma unroll
      for (int i = 0; i < FM; ++i)
        #pragma unroll
        for (int j = 0; j < FN; ++j)
          acc[i][j] = __builtin_amdgcn_mfma_f32_16x16x32_f16(af[i], bfv[j], acc[i][j], 0, 0, 0);
    }
    __syncthreads();                                // also protects staging->tile reuse
  }

  // logits -> fp32 LDS tile
  const int rBase = (lane >> 4) << 2;
  #pragma unroll
  for (int i = 0; i < FM; ++i)
    #pragma unroll
    for (int j = 0; j < FN; ++j)
      #pragma unroll
      for (int r = 0; r < 4; ++r) {
        int row = wm * WTM + i * 16 + rBase + r;    // row < BM == M
        int col = wn * WTN + j * 16 + lr;
        tile[row * TLD + col] = 0.5f * acc[i][j][r] - 0.25f * cn[row];
      }
  __syncthreads();

  // per-column softmax: P threads per column, rows strided
  constexpr int P = 256 / BN;
  const int c = tid & (BN - 1);
  const int p = tid / BN;
  float m = -1e30f;
  for (int j = p; j < M; j += P) m = fmaxf(m, tile[j * TLD + c]);
  redm[p * BN + c] = m;
  __syncthreads();
  float mf = redm[c];
  #pragma unroll
  for (int q = 1; q < P; ++q) mf = fmaxf(mf, redm[q * BN + c]);
  float s = 0.f;
  for (int j = p; j < M; j += P) {
    float e = __expf(tile[j * TLD + c] - mf);
    tile[j * TLD + c] = e;                          // own cells only
    s += e;
  }
  reds[p * BN + c] = s;
  __syncthreads();
  float l = 0.f;
  #pragma unroll
  for (int q = 0; q < P; ++q) l += reds[q * BN + c];
  const float li = 1.f / l;
  for (int j = p; j < M; j += P)
    Eout[(size_t)j * N + nBase + c] = (_Float16)(tile[j * TLD + c] * li);
}

// ---- level-2 merged launch: fused_ls<256,32> (64 blocks) || TANHP gemm (256 blocks) ----
// Independent consumers of h1b; one launch kills a dispatch gap and overlaps tails.
// Unioned LDS: fused needs 36864(stage/tile) + 2048(red) = 38912; gemm needs 24576.
// (256,2): do NOT raise to (256,4) — caps VGPR=64 < fused_ls_body's ~68 (r6 note).
__launch_bounds__(256, 2)
__global__ void lvl2_merged(const _Float16* __restrict__ cb2,
                            const _Float16* __restrict__ h1b,
                            _Float16* __restrict__ E, const float* __restrict__ cn2,
                            const _Float16* __restrict__ Wb2,
                            _Float16* __restrict__ tT, const float* __restrict__ b2) {
  __shared__ __align__(16) char smem[38912];
  if ((int)blockIdx.x < 64) {
    float* redm = (float*)(smem + 36864);
    float* reds = (float*)(smem + 36864 + 1024);
    fused_ls_body<256, 32>(cb2, h1b, E, cn2, 256, 2048, 1024, blockIdx.x * 32,
                           smem, redm, reds);
  } else {
    int lin = blockIdx.x - 64;   // TANHP grid was dim3(8, 32): bx = lin%8, by = lin/8
    gemm_body<128, 64, EP_TANHP>(Wb2, h1b, tT, b2, nullptr, nullptr, 0,
                                 1024, 2048, 1024, 1024, lin % 8, lin / 8, 0,
                                 nullptr, (_Float16*)smem, (_Float16*)(smem + 16384));
  }
}

// ---- level-3 merged launch: fused_ls<32,64> (4 blocks) || TANHP gemm (64 blocks) ----
// Unioned LDS: fused needs 12288 + 2048 = 14336; gemm needs 16384. -> 16384.
__launch_bounds__(256, 2)
__global__ void lvl3_merged(const _Float16* __restrict__ cb3,
                            const _Float16* __restrict__ h2b,
                            _Float16* __restrict__ E, const float* __restrict__ cn3,
                            const _Float16* __restrict__ Wb3,
                            _Float16* __restrict__ tT, const float* __restrict__ b3) {
  __shared__ __align__(16) char smem[16384];
  if ((int)blockIdx.x < 4) {
    float* redm = (float*)(smem + 12288);
    float* reds = (float*)(smem + 12288 + 1024);
    fused_ls_body<32, 64>(cb3, h2b, E, cn3, 32, 256, 1024, blockIdx.x * 64,
                          smem, redm, reds);
  } else {
    int lin = blockIdx.x - 4;    // TANHP grid was dim3(16, 4): bx = lin%16, by = lin/16
    gemm_body<64, 64, EP_TANHP>(Wb3, h2b, tT, b3, nullptr, nullptr, 0,
                                1024, 256, 1024, 1024, lin % 16, lin / 16, 0,
                                nullptr, (_Float16*)smem, (_Float16*)(smem + 8192));
  }
}

extern "C" void kernel_launch(void* const* d_in, const int* in_sizes, int n_in,
                              void* d_out, int out_size, void* d_ws, size_t ws_size,
                              hipStream_t stream) {
  const float* h0 = (const float*)d_in[0];
  const float* c1 = (const float*)d_in[1];
  const float* c2 = (const float*)d_in[2];
  const float* c3 = (const float*)d_in[3];
  const float* W1 = (const float*)d_in[4];
  const float* b1 = (const float*)d_in[5];
  const float* W2 = (const float*)d_in[6];
  const float* b2 = (const float*)d_in[7];
  const float* W3 = (const float*)d_in[8];
  const float* b3 = (const float*)d_in[9];

  const int d = 1024;
  const int N0 = 16384, N1 = 2048, N2 = 256, N3 = 32;

  char* w = (char*)d_ws;
  size_t off = 0;
  auto alloc = [&](size_t bytes) {
    void* p = w + off;
    off += (bytes + 255) & ~(size_t)255;
    return p;
  };
  _Float16* hb  = (_Float16*)alloc((size_t)N0 * d * 2);   // 32 MB
  // A1 = [cb1 (N1 rows); Wb1 (d rows)] contiguous for the merged EP_LT GEMM
  _Float16* A1  = (_Float16*)alloc((size_t)(N1 + d) * d * 2);
  _Float16* cb1 = A1;
  _Float16* Wb1 = A1 + (size_t)N1 * d;
  _Float16* cb2 = (_Float16*)alloc((size_t)N2 * d * 2);
  _Float16* cb3 = (_Float16*)alloc((size_t)N3 * d * 2);
  float* cn1 = (float*)alloc((size_t)N1 * 4);
  float* cn2 = (float*)alloc((size_t)N2 * 4);
  float* cn3 = (float*)alloc((size_t)N3 * 4);
  _Float16* Wb2 = (_Float16*)alloc((size_t)d * d * 2);
  _Float16* Wb3 = (_Float16*)alloc((size_t)d * d * 2);
  _Float16* ST = (_Float16*)alloc((size_t)N1 * N0 * 2);   // 64 MB, E overwrites in place
  _Float16* tT = (_Float16*)alloc((size_t)d * N0 * 2);    // 32 MB
  float* pmax = (float*)alloc((size_t)32 * N0 * 4);       // per-block column maxes (L1)
  float* psum = (float*)alloc((size_t)32 * N0 * 4);       // per-chunk column sums (L1)
  _Float16* h1b = (_Float16*)alloc((size_t)N1 * d * 2);
  _Float16* h2b = (_Float16*)alloc((size_t)N2 * d * 2);
  _Float16* Cpart = (_Float16*)alloc((size_t)8 * N1 * d * 2);  // 32 MB fp16 split-K partials
  _Float16* E = ST;
  (void)ws_size; (void)in_sizes; (void)n_in; (void)out_size;

  // ---- prep: one kernel (casts + center norms) ----
  int nh = N0 * d, nw = d * d;
  int castBlocks = cdiv(nh + 3 * nw, 1024);
  prep<<<castBlocks + N1 + N2 + N3, 256, 0, stream>>>(
      h0, W1, W2, W3, c1, c2, c3, hb, Wb1, Wb2, Wb3, cb1, cb2, cb3,
      cn1, cn2, cn3, nh, nw, castBlocks, N1, N2);

  // ---- level 1: h[16384] -> h1[2048] ----
  // merged logit+tanh GEMM: one B(hb)-sweep computes ST (logit, rows<N1) and
  // tT (tanh, rows>=N1). 1/l applied to tT afterwards by tscale (needs psum).
  gemm_nt<128, 128, EP_LT><<<dim3((N1 + d) / 128, N0 / 128), 256, 0, stream>>>(
      A1, hb, ST, cn1, b1, pmax, /*Ms=*/N1, N1 + d, N0, d, d, tT);
  colexp_partial<<<dim3(N0 / 1024, cdiv(N1, SM_CHUNK)), 256, 0, stream>>>(
      ST, pmax, psum, N1 / 128, N1, N0);
  tscale<<<dim3(N0 / 256, d / 64), 256, 0, stream>>>(tT, psum, cdiv(N1, SM_CHUNK), N0);
  gemm_nt<128, 128, EP_PART><<<dim3(16, 8, 8), 256, 0, stream>>>(
      E, tT, Cpart, nullptr, nullptr, nullptr, 0, N1, d, N0, N0 / 8, nullptr);
  reduce_parts<<<cdiv(N1 * d, 1024), 256, 0, stream>>>(Cpart, h1b, N1 * d, 8);

  // ---- level 2: h1[2048] -> h2[256] (merged: in-block softmax || W2 tanh GEMM) ----
  lvl2_merged<<<64 + 256, 256, 0, stream>>>(cb2, h1b, E, cn2, Wb2, tT, b2);
  gemm_nt<64, 64, EP_PART><<<dim3(4, 16, 8), 256, 0, stream>>>(
      E, tT, Cpart, nullptr, nullptr, nullptr, 0, N2, d, N1, N1 / 8, nullptr);
  reduce_parts<<<cdiv(N2 * d, 1024), 256, 0, stream>>>(Cpart, h2b, N2 * d, 8);

  // ---- level 3: h2[256] -> out[32][1024] fp32 (merged softmax || W3 tanh GEMM) ----
  lvl3_merged<<<4 + 64, 256, 0, stream>>>(cb3, h2b, E, cn3, Wb3, tT, b3);
  gemm_nt<64, 64, EP_F32><<<dim3(1, 16), 256, 0, stream>>>(
      E, tT, d_out, nullptr, nullptr, nullptr, 0, N3, d, N2, N2, nullptr);
}